// Round 7
// baseline (523.211 us; speedup 1.0000x reference)
//
#include <hip/hip_runtime.h>

typedef unsigned short u16;
typedef __attribute__((ext_vector_type(4))) unsigned short u16x4;
typedef __attribute__((ext_vector_type(8))) unsigned short u16x8;
typedef __attribute__((ext_vector_type(8))) short bf16x8;
typedef __attribute__((ext_vector_type(4))) float f32x4;

__device__ __forceinline__ u16 f2bf(float f) {
  union { float f; unsigned u; } v; v.f = f;
  unsigned r = v.u + 0x7fffu + ((v.u >> 16) & 1u);
  return (u16)(r >> 16);
}
__device__ __forceinline__ float bf2f(u16 u) {
  union { unsigned u; float f; } v; v.u = ((unsigned)u) << 16;
  return v.f;
}
// async global->LDS, 16B per lane; LDS dest = wave-uniform base + lane*16
__device__ __forceinline__ void gload16(const void* g, void* l) {
  __builtin_amdgcn_global_load_lds(
      (const __attribute__((address_space(1))) unsigned int*)g,
      (__attribute__((address_space(3))) unsigned int*)l, 16, 0, 0);
}

// ---------------- K0: weight prep (scale folded into Wq, bq) ----------------
__global__ __launch_bounds__(256) void k_prep(
    const float* __restrict__ Wq, const float* __restrict__ Wk,
    const float* __restrict__ bq, const float* __restrict__ bk,
    const float* __restrict__ Wp,
    u16* __restrict__ wqk, u16* __restrict__ wp, float* __restrict__ bqk) {
  int idx = blockIdx.x * 256 + threadIdx.x;
  if (idx < 524288) {
    int o = idx >> 9, hh = idx & 511;
    wqk[idx] = f2bf((o < 512) ? Wq[o * 512 + hh] * 0.125f : Wk[(o - 512) * 512 + hh]);
    wp[idx] = f2bf(Wp[idx]);
  }
  if (idx < 1024) bqk[idx] = (idx < 512) ? bq[idx] * 0.125f : bk[idx - 512];
}

// ---------------- KT1: state (i,s,b,h) -> stT bf16 [(i,b,h)][s] ----------------
__global__ __launch_bounds__(256) void k_transpose_state(
    const float* __restrict__ src, u16* __restrict__ dst) {
  const int i = blockIdx.z, b = blockIdx.y;
  const int s0 = (blockIdx.x & 1) * 64, h0 = (blockIdx.x >> 1) * 64;
  __shared__ u16 T[64][72];
  const int tid = threadIdx.x;
  const int ls = tid >> 4, lh = (tid & 15) * 4;
#pragma unroll
  for (int rr = 0; rr < 4; ++rr) {
    int s = rr * 16 + ls;
    f32x4 v = *(const f32x4*)&src[((i * 128 + s0 + s) * 4 + b) * 512 + h0 + lh];
    u16x4 w4 = { f2bf(v.x), f2bf(v.y), f2bf(v.z), f2bf(v.w) };
    *(u16x4*)&T[s][lh] = w4;
  }
  __syncthreads();
#pragma unroll
  for (int it = 0; it < 2; ++it) {
    int work = it * 256 + tid;
    int hh = work >> 3, sg = (work & 7) * 8;
    u16x8 o;
#pragma unroll
    for (int j = 0; j < 8; ++j) o[j] = T[sg + j][hh];
    *(u16x8*)&dst[((i * 4 + b) * 512 + h0 + hh) * 128 + s0 + sg] = o;
  }
}

// ---------------- KT2: relation (s,t,b,h) -> relT bf16 [(t,b,h)][s] ----------------
__global__ __launch_bounds__(256) void k_transpose_rel(
    const float* __restrict__ src, u16* __restrict__ dst) {
  const int t = blockIdx.z, b = blockIdx.y;
  const int s0 = (blockIdx.x & 1) * 64, h0 = (blockIdx.x >> 1) * 64;
  __shared__ u16 T[64][72];
  const int tid = threadIdx.x;
  const int ls = tid >> 4, lh = (tid & 15) * 4;
#pragma unroll
  for (int rr = 0; rr < 4; ++rr) {
    int s = rr * 16 + ls;
    f32x4 v = *(const f32x4*)&src[(((s0 + s) * 128 + t) * 4 + b) * 512 + h0 + lh];
    u16x4 w4 = { f2bf(v.x), f2bf(v.y), f2bf(v.z), f2bf(v.w) };
    *(u16x4*)&T[s][lh] = w4;
  }
  __syncthreads();
#pragma unroll
  for (int it = 0; it < 2; ++it) {
    int work = it * 256 + tid;
    int hh = work >> 3, sg = (work & 7) * 8;
    u16x8 o;
#pragma unroll
    for (int j = 0; j < 8; ++j) o[j] = T[sg + j][hh];
    *(u16x8*)&dst[((t * 4 + b) * 512 + h0 + hh) * 128 + s0 + sg] = o;
  }
}

// ---------------- K1: q,k projection GEMM (M=65536, N=1024, K=512), bf16 out ----------------
// Grid (8, 512): n0 on x so the 8 blocks sharing one A-tile dispatch back-to-back
// -> A re-reads hit L3 instead of HBM (r6: FETCH was 525MB = 4x state with m0-major).
// B (already bf16) staged via global_load_lds into linear Bs[128*64].
__global__ __launch_bounds__(256) void k_qkproj(
    const float* __restrict__ state, const u16* __restrict__ wqk,
    const float* __restrict__ bqk, u16* __restrict__ qk) {
  const int m0 = blockIdx.y * 128, n0 = blockIdx.x * 128;
  __shared__ u16 smem[17408];  // As[128][72] | Bs[128*64]; epilogue Cs[128][136] overlays
  u16* As = smem;              // 9216 u16
  u16* Bs = smem + 9216;       // 8192 u16
  const int tid = threadIdx.x, lane = tid & 63, wid = tid >> 6;
  const int l15 = lane & 15, l4 = lane >> 4;
  const int wm = (wid >> 1) * 64, wn = (wid & 1) * 64;
  const int lr = lane >> 3, lc = (lane & 7) * 8;  // gload16 row-sub / col (u16)
  const f32x4 fz = {0.f, 0.f, 0.f, 0.f};
  f32x4 acc[4][4];
#pragma unroll
  for (int a = 0; a < 4; ++a)
#pragma unroll
    for (int c = 0; c < 4; ++c) acc[a][c] = fz;
  const int arow = tid >> 3, acol = (tid & 7) * 8;
  for (int k0 = 0; k0 < 512; k0 += 64) {
    __syncthreads();
#pragma unroll
    for (int j = 0; j < 4; ++j) {
      int rb = wid * 32 + j * 8;  // wave-uniform B row base
      gload16(&wqk[(size_t)(n0 + rb + lr) * 512 + k0 + lc], &Bs[rb * 64]);
    }
#pragma unroll
    for (int rr = 0; rr < 4; ++rr) {
      int row = rr * 32 + arow;
      const float* sp = &state[(size_t)(m0 + row) * 512 + k0 + acol];
      f32x4 v0 = *(const f32x4*)sp;
      f32x4 v1 = *(const f32x4*)(sp + 4);
      u16x8 a8 = { f2bf(v0.x), f2bf(v0.y), f2bf(v0.z), f2bf(v0.w),
                   f2bf(v1.x), f2bf(v1.y), f2bf(v1.z), f2bf(v1.w) };
      *(u16x8*)&As[row * 72 + acol] = a8;
    }
    __syncthreads();  // drains vmcnt(0) -> gload16'd B visible
#pragma unroll
    for (int kk = 0; kk < 64; kk += 32) {
      bf16x8 af[4], bfr[4];
#pragma unroll
      for (int mf = 0; mf < 4; ++mf)
        af[mf] = *(const bf16x8*)&As[(wm + mf * 16 + l15) * 72 + kk + l4 * 8];
#pragma unroll
      for (int nf = 0; nf < 4; ++nf)
        bfr[nf] = *(const bf16x8*)&Bs[(wn + nf * 16 + l15) * 64 + kk + l4 * 8];
#pragma unroll
      for (int mf = 0; mf < 4; ++mf)
#pragma unroll
        for (int nf = 0; nf < 4; ++nf)
          acc[mf][nf] = __builtin_amdgcn_mfma_f32_16x16x32_bf16(af[mf], bfr[nf], acc[mf][nf], 0, 0, 0);
    }
  }
  float bias[4];
#pragma unroll
  for (int nf = 0; nf < 4; ++nf) bias[nf] = bqk[n0 + wn + nf * 16 + l15];
  __syncthreads();
  u16* Cs = smem;  // [128][136]
#pragma unroll
  for (int mf = 0; mf < 4; ++mf)
#pragma unroll
    for (int nf = 0; nf < 4; ++nf)
#pragma unroll
      for (int r = 0; r < 4; ++r)
        Cs[(wm + mf * 16 + l4 * 4 + r) * 136 + wn + nf * 16 + l15] =
            f2bf(acc[mf][nf][r] + bias[nf]);
  __syncthreads();
#pragma unroll
  for (int rr = 0; rr < 8; ++rr) {
    int row = rr * 16 + (tid >> 4), c8 = (tid & 15) * 8;
    *(u16x8*)&qk[(size_t)(m0 + row) * 1024 + n0 + c8] = *(const u16x8*)&Cs[row * 136 + c8];
  }
}

// ---------------- K2: per-(i,b) scores -> softmax -> head-mean -> w (bf16) ----------------
__global__ __launch_bounds__(256) void k_scores(
    const u16* __restrict__ qk, const unsigned char* __restrict__ mask,
    u16* __restrict__ wbuf) {
  const int i = blockIdx.x, b = blockIdx.y;
  __shared__ u16 smem[2 * 128 * 72];
  u16* qs = smem;
  u16* ks = smem + 128 * 72;
  const int tid = threadIdx.x, lane = tid & 63, wid = tid >> 6;
  const int l15 = lane & 15, l4 = lane >> 4;
  float wacc[2][8][4];
#pragma unroll
  for (int mf = 0; mf < 2; ++mf)
#pragma unroll
    for (int nf = 0; nf < 8; ++nf)
#pragma unroll
      for (int r = 0; r < 4; ++r) wacc[mf][nf][r] = 0.f;
  bool mk[8];
#pragma unroll
  for (int nf = 0; nf < 8; ++nf) mk[nf] = mask[i * 512 + b * 128 + nf * 16 + l15] != 0;
  const int arow = tid >> 3, acol = (tid & 7) * 8;
  const f32x4 fz = {0.f, 0.f, 0.f, 0.f};
  for (int h = 0; h < 8; ++h) {
    __syncthreads();
#pragma unroll
    for (int rr = 0; rr < 4; ++rr) {
      int row = rr * 32 + arow;
      int base = ((i * 128 + row) * 4 + b) * 1024 + h * 64 + acol;
      *(u16x8*)&qs[row * 72 + acol] = *(const u16x8*)&qk[base];
      *(u16x8*)&ks[row * 72 + acol] = *(const u16x8*)&qk[base + 512];
    }
    __syncthreads();
#pragma unroll
    for (int mf = 0; mf < 2; ++mf) {
      f32x4 sc[8];
#pragma unroll
      for (int nf = 0; nf < 8; ++nf) sc[nf] = fz;
#pragma unroll
      for (int kk = 0; kk < 64; kk += 32) {
        bf16x8 a = *(const bf16x8*)&qs[(wid * 32 + mf * 16 + l15) * 72 + kk + l4 * 8];
#pragma unroll
        for (int nf = 0; nf < 8; ++nf) {
          bf16x8 bb = *(const bf16x8*)&ks[(nf * 16 + l15) * 72 + kk + l4 * 8];
          sc[nf] = __builtin_amdgcn_mfma_f32_16x16x32_bf16(a, bb, sc[nf], 0, 0, 0);
        }
      }
#pragma unroll
      for (int r = 0; r < 4; ++r) {
        float mx = -3e38f;
#pragma unroll
        for (int nf = 0; nf < 8; ++nf) mx = fmaxf(mx, mk[nf] ? -3e38f : sc[nf][r]);
#pragma unroll
        for (int d = 1; d < 16; d <<= 1) mx = fmaxf(mx, __shfl_xor(mx, d, 64));
        float p[8], sum = 0.f;
#pragma unroll
        for (int nf = 0; nf < 8; ++nf) {
          p[nf] = mk[nf] ? 0.f : __expf(sc[nf][r] - mx);
          sum += p[nf];
        }
#pragma unroll
        for (int d = 1; d < 16; d <<= 1) sum += __shfl_xor(sum, d, 64);
        float inv = 0.125f / sum;
#pragma unroll
        for (int nf = 0; nf < 8; ++nf) wacc[mf][nf][r] += p[nf] * inv;
      }
    }
  }
#pragma unroll
  for (int mf = 0; mf < 2; ++mf)
#pragma unroll
    for (int nf = 0; nf < 8; ++nf)
#pragma unroll
      for (int r = 0; r < 4; ++r) {
        int t = wid * 32 + mf * 16 + l4 * 4 + r;
        wbuf[((i * 4 + b) * 128 + t) * 128 + nf * 16 + l15] = f2bf(wacc[mf][nf][r]);
      }
}

// ---------------- K3: x-mix  xT[h][t] = sum_s stT[h][s] * w[t][s], per (i,b,hc) ----------------
__global__ __launch_bounds__(256) void k_xmix(
    const u16* __restrict__ stT, const u16* __restrict__ wbuf,
    u16* __restrict__ xbuf) {
  const int i = blockIdx.x, b = blockIdx.y, hc = blockIdx.z;
  __shared__ u16 smem[2 * 128 * 136];
  u16* ST = smem;
  u16* WS = smem + 128 * 136;
  const int tid = threadIdx.x, lane = tid & 63, wid = tid >> 6;
  const int l15 = lane & 15, l4 = lane >> 4;
  const int wh = (wid >> 1) * 64, wt = (wid & 1) * 64;
  const f32x4 fz = {0.f, 0.f, 0.f, 0.f};
  f32x4 acc[4][4];
#pragma unroll
  for (int a = 0; a < 4; ++a)
#pragma unroll
    for (int c = 0; c < 4; ++c) acc[a][c] = fz;
  const int r16 = tid >> 4, c8 = (tid & 15) * 8;
#pragma unroll
  for (int rr = 0; rr < 8; ++rr) {
    int row = rr * 16 + r16;
    *(u16x8*)&ST[row * 136 + c8] =
        *(const u16x8*)&stT[((i * 4 + b) * 512 + hc * 128 + row) * 128 + c8];
    *(u16x8*)&WS[row * 136 + c8] =
        *(const u16x8*)&wbuf[((i * 4 + b) * 128 + row) * 128 + c8];
  }
  __syncthreads();
#pragma unroll
  for (int kk = 0; kk < 128; kk += 32) {
    bf16x8 af[4], bfr[4];
#pragma unroll
    for (int mf = 0; mf < 4; ++mf)
      af[mf] = *(const bf16x8*)&ST[(wh + mf * 16 + l15) * 136 + kk + l4 * 8];
#pragma unroll
    for (int nf = 0; nf < 4; ++nf)
      bfr[nf] = *(const bf16x8*)&WS[(wt + nf * 16 + l15) * 136 + kk + l4 * 8];
#pragma unroll
    for (int mf = 0; mf < 4; ++mf)
#pragma unroll
      for (int nf = 0; nf < 4; ++nf)
        acc[mf][nf] = __builtin_amdgcn_mfma_f32_16x16x32_bf16(af[mf], bfr[nf], acc[mf][nf], 0, 0, 0);
  }
  __syncthreads();
  u16* Cs = smem;  // [t][h] 128x136
#pragma unroll
  for (int mf = 0; mf < 4; ++mf)
#pragma unroll
    for (int nf = 0; nf < 4; ++nf) {
      int h0 = wh + mf * 16 + l4 * 4;
      int t = wt + nf * 16 + l15;
      u16x4 pk = { f2bf(acc[mf][nf][0]), f2bf(acc[mf][nf][1]),
                   f2bf(acc[mf][nf][2]), f2bf(acc[mf][nf][3]) };
      *(u16x4*)&Cs[t * 136 + h0] = pk;
    }
  __syncthreads();
#pragma unroll
  for (int rr = 0; rr < 8; ++rr) {
    int t = rr * 16 + r16;
    *(u16x8*)&xbuf[((i * 128 + t) * 4 + b) * 512 + hc * 128 + c8] =
        *(const u16x8*)&Cs[t * 136 + c8];
  }
}

// ---------------- K4: rel-mix  relT[h][s] x w2[i][s] -> rel[(i,t,b)][h], per (t,b,hc) ----------------
__global__ __launch_bounds__(256) void k_relmix(
    const u16* __restrict__ relT, const u16* __restrict__ wbuf,
    u16* __restrict__ relbuf) {
  const int t = blockIdx.x, b = blockIdx.y, hc = blockIdx.z;
  __shared__ u16 smem[2 * 128 * 136];
  u16* RT = smem;
  u16* WS = smem + 128 * 136;
  const int tid = threadIdx.x, lane = tid & 63, wid = tid >> 6;
  const int l15 = lane & 15, l4 = lane >> 4;
  const int wh = (wid >> 1) * 64, wi = (wid & 1) * 64;
  const f32x4 fz = {0.f, 0.f, 0.f, 0.f};
  f32x4 acc[4][4];
#pragma unroll
  for (int a = 0; a < 4; ++a)
#pragma unroll
    for (int c = 0; c < 4; ++c) acc[a][c] = fz;
  const int r16 = tid >> 4, c8 = (tid & 15) * 8;
#pragma unroll
  for (int rr = 0; rr < 8; ++rr) {
    int row = rr * 16 + r16;
    *(u16x8*)&RT[row * 136 + c8] =
        *(const u16x8*)&relT[((t * 4 + b) * 512 + hc * 128 + row) * 128 + c8];
    *(u16x8*)&WS[row * 136 + c8] =
        *(const u16x8*)&wbuf[((row * 4 + b) * 128 + t) * 128 + c8];
  }
  __syncthreads();
#pragma unroll
  for (int kk = 0; kk < 128; kk += 32) {
    bf16x8 af[4], bfr[4];
#pragma unroll
    for (int mf = 0; mf < 4; ++mf)
      af[mf] = *(const bf16x8*)&RT[(wh + mf * 16 + l15) * 136 + kk + l4 * 8];
#pragma unroll
    for (int nf = 0; nf < 4; ++nf)
      bfr[nf] = *(const bf16x8*)&WS[(wi + nf * 16 + l15) * 136 + kk + l4 * 8];
#pragma unroll
    for (int mf = 0; mf < 4; ++mf)
#pragma unroll
      for (int nf = 0; nf < 4; ++nf)
        acc[mf][nf] = __builtin_amdgcn_mfma_f32_16x16x32_bf16(af[mf], bfr[nf], acc[mf][nf], 0, 0, 0);
  }
  __syncthreads();
  u16* Cs = smem;  // [i][h] 128x136
#pragma unroll
  for (int mf = 0; mf < 4; ++mf)
#pragma unroll
    for (int nf = 0; nf < 4; ++nf) {
      int h0 = wh + mf * 16 + l4 * 4;
      int ii = wi + nf * 16 + l15;
      u16x4 pk = { f2bf(acc[mf][nf][0]), f2bf(acc[mf][nf][1]),
                   f2bf(acc[mf][nf][2]), f2bf(acc[mf][nf][3]) };
      *(u16x4*)&Cs[ii * 136 + h0] = pk;
    }
  __syncthreads();
#pragma unroll
  for (int rr = 0; rr < 8; ++rr) {
    int ii = rr * 16 + r16;
    *(u16x8*)&relbuf[((ii * 128 + t) * 4 + b) * 512 + hc * 128 + c8] =
        *(const u16x8*)&Cs[ii * 136 + c8];
  }
}

// ---------------- K5a: out-proj GEMM (M=65536,N=512,K=1024) + bias + relu -> yb bf16 ----------------
// Grid (4, 512): n0 on x for A-tile L3 reuse (same mechanism as k_qkproj).
__global__ __launch_bounds__(256) void k_proj(
    const u16* __restrict__ xbuf, const u16* __restrict__ relbuf,
    const u16* __restrict__ wp, const float* __restrict__ bp,
    u16* __restrict__ yb) {
  const int m0 = blockIdx.y * 128, n0 = blockIdx.x * 128;
  __shared__ u16 smem[17408];  // As[128*64] | Bs[128*64]; epilogue Cs[128][136] overlays
  u16* As = smem;
  u16* Bs = smem + 8192;
  const int tid = threadIdx.x, lane = tid & 63, wid = tid >> 6;
  const int l15 = lane & 15, l4 = lane >> 4;
  const int wm = (wid >> 1) * 64, wn = (wid & 1) * 64;
  const int lr = lane >> 3, lc = (lane & 7) * 8;  // staging row-sub / col (u16)
  const f32x4 fz = {0.f, 0.f, 0.f, 0.f};
  f32x4 acc[4][4];
#pragma unroll
  for (int a = 0; a < 4; ++a)
#pragma unroll
    for (int c = 0; c < 4; ++c) acc[a][c] = fz;
  for (int k0 = 0; k0 < 1024; k0 += 64) {
    if (k0) __syncthreads();  // protect As/Bs from previous iteration's readers
    const u16* abase = (k0 < 512) ? xbuf + k0 : relbuf + (k0 - 512);
#pragma unroll
    for (int j = 0; j < 4; ++j) {
      int rb = wid * 32 + j * 8;  // wave-uniform row base within tile
      gload16(&abase[(size_t)(m0 + rb + lr) * 512 + lc], &As[rb * 64]);
      gload16(&wp[(size_t)(n0 + rb + lr) * 1024 + k0 + lc], &Bs[rb * 64]);
    }
    __syncthreads();  // compiler drains vmcnt(0) before s_barrier -> staged data visible
#pragma unroll
    for (int kk = 0; kk < 64; kk += 32) {
      bf16x8 af[4], bfr[4];
#pragma unroll
      for (int mf = 0; mf < 4; ++mf)
        af[mf] = *(const bf16x8*)&As[(wm + mf * 16 + l15) * 64 + kk + l4 * 8];
#pragma unroll
      for (int nf = 0; nf < 4; ++nf)
        bfr[nf] = *(const bf16x8*)&Bs[(wn + nf * 16 + l15) * 64 + kk + l4 * 8];
#pragma unroll
      for (int mf = 0; mf < 4; ++mf)
#pragma unroll
        for (int nf = 0; nf < 4; ++nf)
          acc[mf][nf] = __builtin_amdgcn_mfma_f32_16x16x32_bf16(af[mf], bfr[nf], acc[mf][nf], 0, 0, 0);
    }
  }
  float bias[4];
#pragma unroll
  for (int nf = 0; nf < 4; ++nf) bias[nf] = bp[n0 + wn + nf * 16 + l15];
  __syncthreads();
  u16* Cs = smem;  // [128][136]
#pragma unroll
  for (int mf = 0; mf < 4; ++mf)
#pragma unroll
    for (int nf = 0; nf < 4; ++nf)
#pragma unroll
      for (int r = 0; r < 4; ++r)
        Cs[(wm + mf * 16 + l4 * 4 + r) * 136 + wn + nf * 16 + l15] =
            f2bf(fmaxf(acc[mf][nf][r] + bias[nf], 0.f));
  __syncthreads();
#pragma unroll
  for (int rr = 0; rr < 8; ++rr) {
    int row = rr * 16 + (tid >> 4), c8 = (tid & 15) * 8;
    *(u16x8*)&yb[(size_t)(m0 + row) * 512 + n0 + c8] = *(const u16x8*)&Cs[row * 136 + c8];
  }
}

// ---------------- K5b: residual + LayerNorm (memory-bound row pass) ----------------
__global__ __launch_bounds__(256) void k_ln(
    const u16* __restrict__ yb, const float* __restrict__ state,
    const float* __restrict__ gamma, const float* __restrict__ beta,
    float* __restrict__ out) {
  const int tid = threadIdx.x, lane = tid & 63, wid = tid >> 6;
  f32x4 g0 = *(const f32x4*)&gamma[lane * 8];
  f32x4 g1 = *(const f32x4*)&gamma[lane * 8 + 4];
  f32x4 be0 = *(const f32x4*)&beta[lane * 8];
  f32x4 be1 = *(const f32x4*)&beta[lane * 8 + 4];
  for (int row = blockIdx.x * 4 + wid; row < 65536; row += gridDim.x * 4) {
    size_t gbase = (size_t)row * 512 + lane * 8;
    u16x8 yv = *(const u16x8*)&yb[gbase];
    f32x4 s0 = *(const f32x4*)&state[gbase];
    f32x4 s1 = *(const f32x4*)&state[gbase + 4];
    float y[8];
#pragma unroll
    for (int j = 0; j < 4; ++j) y[j] = bf2f(yv[j]) + s0[j];
#pragma unroll
    for (int j = 0; j < 4; ++j) y[4 + j] = bf2f(yv[4 + j]) + s1[j];
    float sum = 0.f, sq = 0.f;
#pragma unroll
    for (int j = 0; j < 8; ++j) { sum += y[j]; sq += y[j] * y[j]; }
#pragma unroll
    for (int d = 1; d < 64; d <<= 1) { sum += __shfl_xor(sum, d, 64); sq += __shfl_xor(sq, d, 64); }
    float mu = sum * (1.f / 512.f);
    float var = sq * (1.f / 512.f) - mu * mu;
    float rs = rsqrtf(var + 1e-5f);
    f32x4 o0, o1;
#pragma unroll
    for (int j = 0; j < 4; ++j) o0[j] = g0[j] * (y[j] - mu) * rs + be0[j];
#pragma unroll
    for (int j = 0; j < 4; ++j) o1[j] = g1[j] * (y[4 + j] - mu) * rs + be1[j];
    *(f32x4*)&out[gbase] = o0;
    *(f32x4*)&out[gbase + 4] = o1;
  }
}

extern "C" void kernel_launch(void* const* d_in, const int* in_sizes, int n_in,
                              void* d_out, int out_size, void* d_ws, size_t ws_size,
                              hipStream_t stream) {
  const float* state = (const float*)d_in[0];
  const float* relation = (const float*)d_in[1];
  const unsigned char* mask = (const unsigned char*)d_in[2];
  const float* Wq = (const float*)d_in[4];
  const float* bq = (const float*)d_in[5];
  const float* Wk = (const float*)d_in[6];
  const float* bk = (const float*)d_in[7];
  const float* Wp = (const float*)d_in[8];
  const float* bp = (const float*)d_in[9];
  const float* gamma = (const float*)d_in[10];
  const float* beta = (const float*)d_in[11];
  float* out = (float*)d_out;
  char* ws = (char*)d_ws;

  // workspace layout (bytes); x/rel reuse qk region (dead after k_scores);
  // yb reuses stT region (dead after k_xmix).
  u16* qk     = (u16*)(ws);                    // 134,217,728
  u16* xbuf   = (u16*)(ws);                    //  67,108,864 (alias qk lower half)
  u16* relbuf = (u16*)(ws + 67108864);         //  67,108,864 (alias qk upper half)
  u16* stT    = (u16*)(ws + 134217728);        //  67,108,864
  u16* yb     = (u16*)(ws + 134217728);        //  67,108,864 (alias stT)
  u16* relT   = (u16*)(ws + 201326592);        //  67,108,864
  u16* wbuf   = (u16*)(ws + 268435456);        //  16,777,216
  u16* wqk    = (u16*)(ws + 285212672);        //   1,048,576
  u16* wp     = (u16*)(ws + 286261248);        //   1,048,576
  float* bqk  = (float*)(ws + 287309824);      //       4,096

  k_prep<<<2048, 256, 0, stream>>>(Wq, Wk, bq, bk, Wp, wqk, wp, bqk);
  k_qkproj<<<dim3(8, 512), 256, 0, stream>>>(state, wqk, bqk, qk);
  k_transpose_state<<<dim3(16, 4, 128), 256, 0, stream>>>(state, stT);
  k_scores<<<dim3(128, 4), 256, 0, stream>>>(qk, mask, wbuf);
  k_transpose_rel<<<dim3(16, 4, 128), 256, 0, stream>>>(relation, relT);
  k_xmix<<<dim3(128, 4, 4), 256, 0, stream>>>(stT, wbuf, xbuf);
  k_relmix<<<dim3(128, 4, 4), 256, 0, stream>>>(relT, wbuf, relbuf);
  k_proj<<<dim3(4, 512), 256, 0, stream>>>(xbuf, relbuf, wp, bp, yb);
  k_ln<<<2048, 256, 0, stream>>>(yb, state, gamma, beta, out);
}

// Round 8
// 465.979 us; speedup vs baseline: 1.1228x; 1.1228x over previous
//
#include <hip/hip_runtime.h>

typedef unsigned short u16;
typedef __attribute__((ext_vector_type(4))) unsigned short u16x4;
typedef __attribute__((ext_vector_type(8))) unsigned short u16x8;
typedef __attribute__((ext_vector_type(8))) short bf16x8;
typedef __attribute__((ext_vector_type(4))) float f32x4;

__device__ __forceinline__ u16 f2bf(float f) {
  union { float f; unsigned u; } v; v.f = f;
  unsigned r = v.u + 0x7fffu + ((v.u >> 16) & 1u);
  return (u16)(r >> 16);
}
__device__ __forceinline__ float bf2f(u16 u) {
  union { unsigned u; float f; } v; v.u = ((unsigned)u) << 16;
  return v.f;
}
// async global->LDS, 16B per lane; LDS dest = wave-uniform base + lane*16
__device__ __forceinline__ void gload16(const void* g, void* l) {
  __builtin_amdgcn_global_load_lds(
      (const __attribute__((address_space(1))) unsigned int*)g,
      (__attribute__((address_space(3))) unsigned int*)l, 16, 0, 0);
}

// ---------------- K0: weight prep (scale folded into Wq, bq) ----------------
__global__ __launch_bounds__(256) void k_prep(
    const float* __restrict__ Wq, const float* __restrict__ Wk,
    const float* __restrict__ bq, const float* __restrict__ bk,
    const float* __restrict__ Wp,
    u16* __restrict__ wqk, u16* __restrict__ wp, float* __restrict__ bqk) {
  int idx = blockIdx.x * 256 + threadIdx.x;
  if (idx < 524288) {
    int o = idx >> 9, hh = idx & 511;
    wqk[idx] = f2bf((o < 512) ? Wq[o * 512 + hh] * 0.125f : Wk[(o - 512) * 512 + hh]);
    wp[idx] = f2bf(Wp[idx]);
  }
  if (idx < 1024) bqk[idx] = (idx < 512) ? bq[idx] * 0.125f : bk[idx - 512];
}

// ---------------- KT1: state (i,s,b,h) -> stT bf16 [(i,b,h)][s]  AND  stB bf16 flat copy ----------------
// stB[((i*128+s)*4+b)*512+h] = bf16(state[...]) -- consumed by k_qkproj (kills its 8x-repeated f2bf).
__global__ __launch_bounds__(256) void k_transpose_state(
    const float* __restrict__ src, u16* __restrict__ dst, u16* __restrict__ stB) {
  const int i = blockIdx.z, b = blockIdx.y;
  const int s0 = (blockIdx.x & 1) * 64, h0 = (blockIdx.x >> 1) * 64;
  __shared__ u16 T[64][72];
  const int tid = threadIdx.x;
  const int ls = tid >> 4, lh = (tid & 15) * 4;
#pragma unroll
  for (int rr = 0; rr < 4; ++rr) {
    int s = rr * 16 + ls;
    size_t flat = ((size_t)(i * 128 + s0 + s) * 4 + b) * 512 + h0 + lh;
    f32x4 v = *(const f32x4*)&src[flat];
    u16x4 w4 = { f2bf(v.x), f2bf(v.y), f2bf(v.z), f2bf(v.w) };
    *(u16x4*)&T[s][lh] = w4;
    *(u16x4*)&stB[flat] = w4;
  }
  __syncthreads();
#pragma unroll
  for (int it = 0; it < 2; ++it) {
    int work = it * 256 + tid;
    int hh = work >> 3, sg = (work & 7) * 8;
    u16x8 o;
#pragma unroll
    for (int j = 0; j < 8; ++j) o[j] = T[sg + j][hh];
    *(u16x8*)&dst[((i * 4 + b) * 512 + h0 + hh) * 128 + s0 + sg] = o;
  }
}

// ---------------- KT2: relation (s,t,b,h) -> relT bf16 [(t,b,h)][s] ----------------
__global__ __launch_bounds__(256) void k_transpose_rel(
    const float* __restrict__ src, u16* __restrict__ dst) {
  const int t = blockIdx.z, b = blockIdx.y;
  const int s0 = (blockIdx.x & 1) * 64, h0 = (blockIdx.x >> 1) * 64;
  __shared__ u16 T[64][72];
  const int tid = threadIdx.x;
  const int ls = tid >> 4, lh = (tid & 15) * 4;
#pragma unroll
  for (int rr = 0; rr < 4; ++rr) {
    int s = rr * 16 + ls;
    f32x4 v = *(const f32x4*)&src[(((s0 + s) * 128 + t) * 4 + b) * 512 + h0 + lh];
    u16x4 w4 = { f2bf(v.x), f2bf(v.y), f2bf(v.z), f2bf(v.w) };
    *(u16x4*)&T[s][lh] = w4;
  }
  __syncthreads();
#pragma unroll
  for (int it = 0; it < 2; ++it) {
    int work = it * 256 + tid;
    int hh = work >> 3, sg = (work & 7) * 8;
    u16x8 o;
#pragma unroll
    for (int j = 0; j < 8; ++j) o[j] = T[sg + j][hh];
    *(u16x8*)&dst[((t * 4 + b) * 512 + h0 + hh) * 128 + s0 + sg] = o;
  }
}

// ---------------- K1: q,k projection GEMM (M=65536, N=1024, K=512), bf16 in/out ----------------
// m97 clone of k_proj: both operands via global_load_lds into linear LDS, no VALU cast.
__global__ __launch_bounds__(256) void k_qkproj(
    const u16* __restrict__ stB, const u16* __restrict__ wqk,
    const float* __restrict__ bqk, u16* __restrict__ qk) {
  const int m0 = blockIdx.y * 128, n0 = blockIdx.x * 128;
  __shared__ u16 smem[17408];  // As[128*64] | Bs[128*64]; epilogue Cs[128][136] overlays
  u16* As = smem;
  u16* Bs = smem + 8192;
  const int tid = threadIdx.x, lane = tid & 63, wid = tid >> 6;
  const int l15 = lane & 15, l4 = lane >> 4;
  const int wm = (wid >> 1) * 64, wn = (wid & 1) * 64;
  const int lr = lane >> 3, lc = (lane & 7) * 8;
  const f32x4 fz = {0.f, 0.f, 0.f, 0.f};
  f32x4 acc[4][4];
#pragma unroll
  for (int a = 0; a < 4; ++a)
#pragma unroll
    for (int c = 0; c < 4; ++c) acc[a][c] = fz;
  for (int k0 = 0; k0 < 512; k0 += 64) {
    if (k0) __syncthreads();
#pragma unroll
    for (int j = 0; j < 4; ++j) {
      int rb = wid * 32 + j * 8;  // wave-uniform row base
      gload16(&stB[(size_t)(m0 + rb + lr) * 512 + k0 + lc], &As[rb * 64]);
      gload16(&wqk[(size_t)(n0 + rb + lr) * 512 + k0 + lc], &Bs[rb * 64]);
    }
    __syncthreads();  // drains vmcnt(0) -> staged data visible
#pragma unroll
    for (int kk = 0; kk < 64; kk += 32) {
      bf16x8 af[4], bfr[4];
#pragma unroll
      for (int mf = 0; mf < 4; ++mf)
        af[mf] = *(const bf16x8*)&As[(wm + mf * 16 + l15) * 64 + kk + l4 * 8];
#pragma unroll
      for (int nf = 0; nf < 4; ++nf)
        bfr[nf] = *(const bf16x8*)&Bs[(wn + nf * 16 + l15) * 64 + kk + l4 * 8];
#pragma unroll
      for (int mf = 0; mf < 4; ++mf)
#pragma unroll
        for (int nf = 0; nf < 4; ++nf)
          acc[mf][nf] = __builtin_amdgcn_mfma_f32_16x16x32_bf16(af[mf], bfr[nf], acc[mf][nf], 0, 0, 0);
    }
  }
  float bias[4];
#pragma unroll
  for (int nf = 0; nf < 4; ++nf) bias[nf] = bqk[n0 + wn + nf * 16 + l15];
  __syncthreads();
  u16* Cs = smem;  // [128][136]
#pragma unroll
  for (int mf = 0; mf < 4; ++mf)
#pragma unroll
    for (int nf = 0; nf < 4; ++nf)
#pragma unroll
      for (int r = 0; r < 4; ++r)
        Cs[(wm + mf * 16 + l4 * 4 + r) * 136 + wn + nf * 16 + l15] =
            f2bf(acc[mf][nf][r] + bias[nf]);
  __syncthreads();
#pragma unroll
  for (int rr = 0; rr < 8; ++rr) {
    int row = rr * 16 + (tid >> 4), c8 = (tid & 15) * 8;
    *(u16x8*)&qk[(size_t)(m0 + row) * 1024 + n0 + c8] = *(const u16x8*)&Cs[row * 136 + c8];
  }
}

// ---------------- K2: per-(i,b) scores -> softmax -> head-mean -> w (bf16) ----------------
__global__ __launch_bounds__(256) void k_scores(
    const u16* __restrict__ qk, const unsigned char* __restrict__ mask,
    u16* __restrict__ wbuf) {
  const int i = blockIdx.x, b = blockIdx.y;
  __shared__ u16 smem[2 * 128 * 72];
  u16* qs = smem;
  u16* ks = smem + 128 * 72;
  const int tid = threadIdx.x, lane = tid & 63, wid = tid >> 6;
  const int l15 = lane & 15, l4 = lane >> 4;
  float wacc[2][8][4];
#pragma unroll
  for (int mf = 0; mf < 2; ++mf)
#pragma unroll
    for (int nf = 0; nf < 8; ++nf)
#pragma unroll
      for (int r = 0; r < 4; ++r) wacc[mf][nf][r] = 0.f;
  bool mk[8];
#pragma unroll
  for (int nf = 0; nf < 8; ++nf) mk[nf] = mask[i * 512 + b * 128 + nf * 16 + l15] != 0;
  const int arow = tid >> 3, acol = (tid & 7) * 8;
  const f32x4 fz = {0.f, 0.f, 0.f, 0.f};
  for (int h = 0; h < 8; ++h) {
    __syncthreads();
#pragma unroll
    for (int rr = 0; rr < 4; ++rr) {
      int row = rr * 32 + arow;
      int base = ((i * 128 + row) * 4 + b) * 1024 + h * 64 + acol;
      *(u16x8*)&qs[row * 72 + acol] = *(const u16x8*)&qk[base];
      *(u16x8*)&ks[row * 72 + acol] = *(const u16x8*)&qk[base + 512];
    }
    __syncthreads();
#pragma unroll
    for (int mf = 0; mf < 2; ++mf) {
      f32x4 sc[8];
#pragma unroll
      for (int nf = 0; nf < 8; ++nf) sc[nf] = fz;
#pragma unroll
      for (int kk = 0; kk < 64; kk += 32) {
        bf16x8 a = *(const bf16x8*)&qs[(wid * 32 + mf * 16 + l15) * 72 + kk + l4 * 8];
#pragma unroll
        for (int nf = 0; nf < 8; ++nf) {
          bf16x8 bb = *(const bf16x8*)&ks[(nf * 16 + l15) * 72 + kk + l4 * 8];
          sc[nf] = __builtin_amdgcn_mfma_f32_16x16x32_bf16(a, bb, sc[nf], 0, 0, 0);
        }
      }
#pragma unroll
      for (int r = 0; r < 4; ++r) {
        float mx = -3e38f;
#pragma unroll
        for (int nf = 0; nf < 8; ++nf) mx = fmaxf(mx, mk[nf] ? -3e38f : sc[nf][r]);
#pragma unroll
        for (int d = 1; d < 16; d <<= 1) mx = fmaxf(mx, __shfl_xor(mx, d, 64));
        float p[8], sum = 0.f;
#pragma unroll
        for (int nf = 0; nf < 8; ++nf) {
          p[nf] = mk[nf] ? 0.f : __expf(sc[nf][r] - mx);
          sum += p[nf];
        }
#pragma unroll
        for (int d = 1; d < 16; d <<= 1) sum += __shfl_xor(sum, d, 64);
        float inv = 0.125f / sum;
#pragma unroll
        for (int nf = 0; nf < 8; ++nf) wacc[mf][nf][r] += p[nf] * inv;
      }
    }
  }
#pragma unroll
  for (int mf = 0; mf < 2; ++mf)
#pragma unroll
    for (int nf = 0; nf < 8; ++nf)
#pragma unroll
      for (int r = 0; r < 4; ++r) {
        int t = wid * 32 + mf * 16 + l4 * 4 + r;
        wbuf[((i * 4 + b) * 128 + t) * 128 + nf * 16 + l15] = f2bf(wacc[mf][nf][r]);
      }
}

// ---------------- K3: x-mix  xT[h][t] = sum_s stT[h][s] * w[t][s], per (i,b,hc) ----------------
__global__ __launch_bounds__(256) void k_xmix(
    const u16* __restrict__ stT, const u16* __restrict__ wbuf,
    u16* __restrict__ xbuf) {
  const int i = blockIdx.x, b = blockIdx.y, hc = blockIdx.z;
  __shared__ u16 smem[2 * 128 * 136];
  u16* ST = smem;
  u16* WS = smem + 128 * 136;
  const int tid = threadIdx.x, lane = tid & 63, wid = tid >> 6;
  const int l15 = lane & 15, l4 = lane >> 4;
  const int wh = (wid >> 1) * 64, wt = (wid & 1) * 64;
  const f32x4 fz = {0.f, 0.f, 0.f, 0.f};
  f32x4 acc[4][4];
#pragma unroll
  for (int a = 0; a < 4; ++a)
#pragma unroll
    for (int c = 0; c < 4; ++c) acc[a][c] = fz;
  const int r16 = tid >> 4, c8 = (tid & 15) * 8;
#pragma unroll
  for (int rr = 0; rr < 8; ++rr) {
    int row = rr * 16 + r16;
    *(u16x8*)&ST[row * 136 + c8] =
        *(const u16x8*)&stT[((i * 4 + b) * 512 + hc * 128 + row) * 128 + c8];
    *(u16x8*)&WS[row * 136 + c8] =
        *(const u16x8*)&wbuf[((i * 4 + b) * 128 + row) * 128 + c8];
  }
  __syncthreads();
#pragma unroll
  for (int kk = 0; kk < 128; kk += 32) {
    bf16x8 af[4], bfr[4];
#pragma unroll
    for (int mf = 0; mf < 4; ++mf)
      af[mf] = *(const bf16x8*)&ST[(wh + mf * 16 + l15) * 136 + kk + l4 * 8];
#pragma unroll
    for (int nf = 0; nf < 4; ++nf)
      bfr[nf] = *(const bf16x8*)&WS[(wt + nf * 16 + l15) * 136 + kk + l4 * 8];
#pragma unroll
    for (int mf = 0; mf < 4; ++mf)
#pragma unroll
      for (int nf = 0; nf < 4; ++nf)
        acc[mf][nf] = __builtin_amdgcn_mfma_f32_16x16x32_bf16(af[mf], bfr[nf], acc[mf][nf], 0, 0, 0);
  }
  __syncthreads();
  u16* Cs = smem;  // [t][h] 128x136
#pragma unroll
  for (int mf = 0; mf < 4; ++mf)
#pragma unroll
    for (int nf = 0; nf < 4; ++nf) {
      int h0 = wh + mf * 16 + l4 * 4;
      int t = wt + nf * 16 + l15;
      u16x4 pk = { f2bf(acc[mf][nf][0]), f2bf(acc[mf][nf][1]),
                   f2bf(acc[mf][nf][2]), f2bf(acc[mf][nf][3]) };
      *(u16x4*)&Cs[t * 136 + h0] = pk;
    }
  __syncthreads();
#pragma unroll
  for (int rr = 0; rr < 8; ++rr) {
    int t = rr * 16 + r16;
    *(u16x8*)&xbuf[((i * 128 + t) * 4 + b) * 512 + hc * 128 + c8] =
        *(const u16x8*)&Cs[t * 136 + c8];
  }
}

// ---------------- K4: rel-mix  relT[h][s] x w2[i][s] -> rel[(i,t,b)][h], per (t,b,hc) ----------------
__global__ __launch_bounds__(256) void k_relmix(
    const u16* __restrict__ relT, const u16* __restrict__ wbuf,
    u16* __restrict__ relbuf) {
  const int t = blockIdx.x, b = blockIdx.y, hc = blockIdx.z;
  __shared__ u16 smem[2 * 128 * 136];
  u16* RT = smem;
  u16* WS = smem + 128 * 136;
  const int tid = threadIdx.x, lane = tid & 63, wid = tid >> 6;
  const int l15 = lane & 15, l4 = lane >> 4;
  const int wh = (wid >> 1) * 64, wi = (wid & 1) * 64;
  const f32x4 fz = {0.f, 0.f, 0.f, 0.f};
  f32x4 acc[4][4];
#pragma unroll
  for (int a = 0; a < 4; ++a)
#pragma unroll
    for (int c = 0; c < 4; ++c) acc[a][c] = fz;
  const int r16 = tid >> 4, c8 = (tid & 15) * 8;
#pragma unroll
  for (int rr = 0; rr < 8; ++rr) {
    int row = rr * 16 + r16;
    *(u16x8*)&RT[row * 136 + c8] =
        *(const u16x8*)&relT[((t * 4 + b) * 512 + hc * 128 + row) * 128 + c8];
    *(u16x8*)&WS[row * 136 + c8] =
        *(const u16x8*)&wbuf[((row * 4 + b) * 128 + t) * 128 + c8];
  }
  __syncthreads();
#pragma unroll
  for (int kk = 0; kk < 128; kk += 32) {
    bf16x8 af[4], bfr[4];
#pragma unroll
    for (int mf = 0; mf < 4; ++mf)
      af[mf] = *(const bf16x8*)&RT[(wh + mf * 16 + l15) * 136 + kk + l4 * 8];
#pragma unroll
    for (int nf = 0; nf < 4; ++nf)
      bfr[nf] = *(const bf16x8*)&WS[(wi + nf * 16 + l15) * 136 + kk + l4 * 8];
#pragma unroll
    for (int mf = 0; mf < 4; ++mf)
#pragma unroll
      for (int nf = 0; nf < 4; ++nf)
        acc[mf][nf] = __builtin_amdgcn_mfma_f32_16x16x32_bf16(af[mf], bfr[nf], acc[mf][nf], 0, 0, 0);
  }
  __syncthreads();
  u16* Cs = smem;  // [i][h] 128x136
#pragma unroll
  for (int mf = 0; mf < 4; ++mf)
#pragma unroll
    for (int nf = 0; nf < 4; ++nf) {
      int h0 = wh + mf * 16 + l4 * 4;
      int ii = wi + nf * 16 + l15;
      u16x4 pk = { f2bf(acc[mf][nf][0]), f2bf(acc[mf][nf][1]),
                   f2bf(acc[mf][nf][2]), f2bf(acc[mf][nf][3]) };
      *(u16x4*)&Cs[ii * 136 + h0] = pk;
    }
  __syncthreads();
#pragma unroll
  for (int rr = 0; rr < 8; ++rr) {
    int ii = rr * 16 + r16;
    *(u16x8*)&relbuf[((ii * 128 + t) * 4 + b) * 512 + hc * 128 + c8] =
        *(const u16x8*)&Cs[ii * 136 + c8];
  }
}

// ---------------- K5a: out-proj GEMM (M=65536,N=512,K=1024) + bias + relu -> yb bf16 ----------------
__global__ __launch_bounds__(256) void k_proj(
    const u16* __restrict__ xbuf, const u16* __restrict__ relbuf,
    const u16* __restrict__ wp, const float* __restrict__ bp,
    u16* __restrict__ yb) {
  const int m0 = blockIdx.y * 128, n0 = blockIdx.x * 128;
  __shared__ u16 smem[17408];  // As[128*64] | Bs[128*64]; epilogue Cs[128][136] overlays
  u16* As = smem;
  u16* Bs = smem + 8192;
  const int tid = threadIdx.x, lane = tid & 63, wid = tid >> 6;
  const int l15 = lane & 15, l4 = lane >> 4;
  const int wm = (wid >> 1) * 64, wn = (wid & 1) * 64;
  const int lr = lane >> 3, lc = (lane & 7) * 8;  // staging row-sub / col (u16)
  const f32x4 fz = {0.f, 0.f, 0.f, 0.f};
  f32x4 acc[4][4];
#pragma unroll
  for (int a = 0; a < 4; ++a)
#pragma unroll
    for (int c = 0; c < 4; ++c) acc[a][c] = fz;
  for (int k0 = 0; k0 < 1024; k0 += 64) {
    if (k0) __syncthreads();  // protect As/Bs from previous iteration's readers
    const u16* abase = (k0 < 512) ? xbuf + k0 : relbuf + (k0 - 512);
#pragma unroll
    for (int j = 0; j < 4; ++j) {
      int rb = wid * 32 + j * 8;  // wave-uniform row base within tile
      gload16(&abase[(size_t)(m0 + rb + lr) * 512 + lc], &As[rb * 64]);
      gload16(&wp[(size_t)(n0 + rb + lr) * 1024 + k0 + lc], &Bs[rb * 64]);
    }
    __syncthreads();  // compiler drains vmcnt(0) before s_barrier -> staged data visible
#pragma unroll
    for (int kk = 0; kk < 64; kk += 32) {
      bf16x8 af[4], bfr[4];
#pragma unroll
      for (int mf = 0; mf < 4; ++mf)
        af[mf] = *(const bf16x8*)&As[(wm + mf * 16 + l15) * 64 + kk + l4 * 8];
#pragma unroll
      for (int nf = 0; nf < 4; ++nf)
        bfr[nf] = *(const bf16x8*)&Bs[(wn + nf * 16 + l15) * 64 + kk + l4 * 8];
#pragma unroll
      for (int mf = 0; mf < 4; ++mf)
#pragma unroll
        for (int nf = 0; nf < 4; ++nf)
          acc[mf][nf] = __builtin_amdgcn_mfma_f32_16x16x32_bf16(af[mf], bfr[nf], acc[mf][nf], 0, 0, 0);
    }
  }
  float bias[4];
#pragma unroll
  for (int nf = 0; nf < 4; ++nf) bias[nf] = bp[n0 + wn + nf * 16 + l15];
  __syncthreads();
  u16* Cs = smem;  // [128][136]
#pragma unroll
  for (int mf = 0; mf < 4; ++mf)
#pragma unroll
    for (int nf = 0; nf < 4; ++nf)
#pragma unroll
      for (int r = 0; r < 4; ++r)
        Cs[(wm + mf * 16 + l4 * 4 + r) * 136 + wn + nf * 16 + l15] =
            f2bf(fmaxf(acc[mf][nf][r] + bias[nf], 0.f));
  __syncthreads();
#pragma unroll
  for (int rr = 0; rr < 8; ++rr) {
    int row = rr * 16 + (tid >> 4), c8 = (tid & 15) * 8;
    *(u16x8*)&yb[(size_t)(m0 + row) * 512 + n0 + c8] = *(const u16x8*)&Cs[row * 136 + c8];
  }
}

// ---------------- K5b: residual + LayerNorm (memory-bound row pass) ----------------
__global__ __launch_bounds__(256) void k_ln(
    const u16* __restrict__ yb, const float* __restrict__ state,
    const float* __restrict__ gamma, const float* __restrict__ beta,
    float* __restrict__ out) {
  const int tid = threadIdx.x, lane = tid & 63, wid = tid >> 6;
  f32x4 g0 = *(const f32x4*)&gamma[lane * 8];
  f32x4 g1 = *(const f32x4*)&gamma[lane * 8 + 4];
  f32x4 be0 = *(const f32x4*)&beta[lane * 8];
  f32x4 be1 = *(const f32x4*)&beta[lane * 8 + 4];
  for (int row = blockIdx.x * 4 + wid; row < 65536; row += gridDim.x * 4) {
    size_t gbase = (size_t)row * 512 + lane * 8;
    u16x8 yv = *(const u16x8*)&yb[gbase];
    f32x4 s0 = *(const f32x4*)&state[gbase];
    f32x4 s1 = *(const f32x4*)&state[gbase + 4];
    float y[8];
#pragma unroll
    for (int j = 0; j < 4; ++j) y[j] = bf2f(yv[j]) + s0[j];
#pragma unroll
    for (int j = 0; j < 4; ++j) y[4 + j] = bf2f(yv[4 + j]) + s1[j];
    float sum = 0.f, sq = 0.f;
#pragma unroll
    for (int j = 0; j < 8; ++j) { sum += y[j]; sq += y[j] * y[j]; }
#pragma unroll
    for (int d = 1; d < 64; d <<= 1) { sum += __shfl_xor(sum, d, 64); sq += __shfl_xor(sq, d, 64); }
    float mu = sum * (1.f / 512.f);
    float var = sq * (1.f / 512.f) - mu * mu;
    float rs = rsqrtf(var + 1e-5f);
    f32x4 o0, o1;
#pragma unroll
    for (int j = 0; j < 4; ++j) o0[j] = g0[j] * (y[j] - mu) * rs + be0[j];
#pragma unroll
    for (int j = 0; j < 4; ++j) o1[j] = g1[j] * (y[4 + j] - mu) * rs + be1[j];
    *(f32x4*)&out[gbase] = o0;
    *(f32x4*)&out[gbase + 4] = o1;
  }
}

extern "C" void kernel_launch(void* const* d_in, const int* in_sizes, int n_in,
                              void* d_out, int out_size, void* d_ws, size_t ws_size,
                              hipStream_t stream) {
  const float* state = (const float*)d_in[0];
  const float* relation = (const float*)d_in[1];
  const unsigned char* mask = (const unsigned char*)d_in[2];
  const float* Wq = (const float*)d_in[4];
  const float* bq = (const float*)d_in[5];
  const float* Wk = (const float*)d_in[6];
  const float* bk = (const float*)d_in[7];
  const float* Wp = (const float*)d_in[8];
  const float* bp = (const float*)d_in[9];
  const float* gamma = (const float*)d_in[10];
  const float* beta = (const float*)d_in[11];
  float* out = (float*)d_out;
  char* ws = (char*)d_ws;

  // workspace layout (bytes); aliases (lifetimes disjoint):
  //   xbuf/relbuf alias qk (dead after k_scores)
  //   yb aliases stT (dead after k_xmix)
  //   stB aliases relT (relT written later by k_transpose_rel; stB dead after k_qkproj)
  u16* qk     = (u16*)(ws);                    // 134,217,728
  u16* xbuf   = (u16*)(ws);                    //  67,108,864 (alias qk lower half)
  u16* relbuf = (u16*)(ws + 67108864);         //  67,108,864 (alias qk upper half)
  u16* stT    = (u16*)(ws + 134217728);        //  67,108,864
  u16* yb     = (u16*)(ws + 134217728);        //  67,108,864 (alias stT)
  u16* relT   = (u16*)(ws + 201326592);        //  67,108,864
  u16* stB    = (u16*)(ws + 201326592);        //  67,108,864 (alias relT)
  u16* wbuf   = (u16*)(ws + 268435456);        //  16,777,216
  u16* wqk    = (u16*)(ws + 285212672);        //   1,048,576
  u16* wp     = (u16*)(ws + 286261248);        //   1,048,576
  float* bqk  = (float*)(ws + 287309824);      //       4,096

  k_prep<<<2048, 256, 0, stream>>>(Wq, Wk, bq, bk, Wp, wqk, wp, bqk);
  k_transpose_state<<<dim3(16, 4, 128), 256, 0, stream>>>(state, stT, stB);
  k_qkproj<<<dim3(8, 512), 256, 0, stream>>>(stB, wqk, bqk, qk);
  k_scores<<<dim3(128, 4), 256, 0, stream>>>(qk, mask, wbuf);
  k_transpose_rel<<<dim3(16, 4, 128), 256, 0, stream>>>(relation, relT);
  k_xmix<<<dim3(128, 4, 4), 256, 0, stream>>>(stT, wbuf, xbuf);
  k_relmix<<<dim3(128, 4, 4), 256, 0, stream>>>(relT, wbuf, relbuf);
  k_proj<<<dim3(4, 512), 256, 0, stream>>>(xbuf, relbuf, wp, bp, yb);
  k_ln<<<2048, 256, 0, stream>>>(yb, state, gamma, beta, out);
}

// Round 9
// 441.602 us; speedup vs baseline: 1.1848x; 1.0552x over previous
//
#include <hip/hip_runtime.h>

typedef unsigned short u16;
typedef __attribute__((ext_vector_type(4))) unsigned short u16x4;
typedef __attribute__((ext_vector_type(8))) unsigned short u16x8;
typedef __attribute__((ext_vector_type(8))) short bf16x8;
typedef __attribute__((ext_vector_type(4))) float f32x4;

__device__ __forceinline__ u16 f2bf(float f) {
  union { float f; unsigned u; } v; v.f = f;
  unsigned r = v.u + 0x7fffu + ((v.u >> 16) & 1u);
  return (u16)(r >> 16);
}
__device__ __forceinline__ float bf2f(u16 u) {
  union { unsigned u; float f; } v; v.u = ((unsigned)u) << 16;
  return v.f;
}
__device__ __forceinline__ u16x8 pack8(f32x4 a, f32x4 b) {
  u16x8 r = { f2bf(a.x), f2bf(a.y), f2bf(a.z), f2bf(a.w),
              f2bf(b.x), f2bf(b.y), f2bf(b.z), f2bf(b.w) };
  return r;
}
// async global->LDS, 16B per lane; LDS dest = wave-uniform base + lane*16
__device__ __forceinline__ void gload16(const void* g, void* l) {
  __builtin_amdgcn_global_load_lds(
      (const __attribute__((address_space(1))) unsigned int*)g,
      (__attribute__((address_space(3))) unsigned int*)l, 16, 0, 0);
}

// ---------------- K0: weight prep (scale folded into Wq, bq) ----------------
__global__ __launch_bounds__(256) void k_prep(
    const float* __restrict__ Wq, const float* __restrict__ Wk,
    const float* __restrict__ bq, const float* __restrict__ bk,
    const float* __restrict__ Wp,
    u16* __restrict__ wqk, u16* __restrict__ wp, float* __restrict__ bqk) {
  int idx = blockIdx.x * 256 + threadIdx.x;
  if (idx < 524288) {
    int o = idx >> 9, hh = idx & 511;
    wqk[idx] = f2bf((o < 512) ? Wq[o * 512 + hh] * 0.125f : Wk[(o - 512) * 512 + hh]);
    wp[idx] = f2bf(Wp[idx]);
  }
  if (idx < 1024) bqk[idx] = (idx < 512) ? bq[idx] * 0.125f : bk[idx - 512];
}

// ---------------- KT1: state (i,s,b,h) -> stT bf16 [(i,b,h)][s]  AND  stB bf16 flat copy ----------------
__global__ __launch_bounds__(256) void k_transpose_state(
    const float* __restrict__ src, u16* __restrict__ dst, u16* __restrict__ stB) {
  const int i = blockIdx.z, b = blockIdx.y;
  const int s0 = (blockIdx.x & 1) * 64, h0 = (blockIdx.x >> 1) * 64;
  __shared__ u16 T[64][72];
  const int tid = threadIdx.x;
  const int ls = tid >> 4, lh = (tid & 15) * 4;
#pragma unroll
  for (int rr = 0; rr < 4; ++rr) {
    int s = rr * 16 + ls;
    size_t flat = ((size_t)(i * 128 + s0 + s) * 4 + b) * 512 + h0 + lh;
    f32x4 v = *(const f32x4*)&src[flat];
    u16x4 w4 = { f2bf(v.x), f2bf(v.y), f2bf(v.z), f2bf(v.w) };
    *(u16x4*)&T[s][lh] = w4;
    *(u16x4*)&stB[flat] = w4;
  }
  __syncthreads();
#pragma unroll
  for (int it = 0; it < 2; ++it) {
    int work = it * 256 + tid;
    int hh = work >> 3, sg = (work & 7) * 8;
    u16x8 o;
#pragma unroll
    for (int j = 0; j < 8; ++j) o[j] = T[sg + j][hh];
    *(u16x8*)&dst[((i * 4 + b) * 512 + h0 + hh) * 128 + s0 + sg] = o;
  }
}

// ---------------- K1: q,k projection GEMM (M=65536, N=1024, K=512), bf16 in/out ----------------
// 1D grid 4096, XCD-chunked swizzle: all 8 n-blocks of one m-strip land on ONE XCD,
// 8 ids apart in dispatch -> A-strip (128KB) L2-resident, reused 8x (r8: FETCH was 4x ideal).
__global__ __launch_bounds__(256) void k_qkproj(
    const u16* __restrict__ stB, const u16* __restrict__ wqk,
    const float* __restrict__ bqk, u16* __restrict__ qk) {
  const int flat = blockIdx.x;
  const int xcd = flat & 7, local = flat >> 3;          // local 0..511
  const int m0 = (xcd * 64 + (local >> 3)) * 128;       // 512 m-tiles, 64 per XCD
  const int n0 = (local & 7) * 128;                     // 8 n-tiles
  __shared__ u16 smem[17408];  // As[128*64] | Bs[128*64]; epilogue Cs[128][136] overlays
  u16* As = smem;
  u16* Bs = smem + 8192;
  const int tid = threadIdx.x, lane = tid & 63, wid = tid >> 6;
  const int l15 = lane & 15, l4 = lane >> 4;
  const int wm = (wid >> 1) * 64, wn = (wid & 1) * 64;
  const int lr = lane >> 3, lc = (lane & 7) * 8;
  const f32x4 fz = {0.f, 0.f, 0.f, 0.f};
  f32x4 acc[4][4];
#pragma unroll
  for (int a = 0; a < 4; ++a)
#pragma unroll
    for (int c = 0; c < 4; ++c) acc[a][c] = fz;
  for (int k0 = 0; k0 < 512; k0 += 64) {
    if (k0) __syncthreads();
#pragma unroll
    for (int j = 0; j < 4; ++j) {
      int rb = wid * 32 + j * 8;  // wave-uniform row base
      gload16(&stB[(size_t)(m0 + rb + lr) * 512 + k0 + lc], &As[rb * 64]);
      gload16(&wqk[(size_t)(n0 + rb + lr) * 512 + k0 + lc], &Bs[rb * 64]);
    }
    __syncthreads();  // drains vmcnt(0) -> staged data visible
#pragma unroll
    for (int kk = 0; kk < 64; kk += 32) {
      bf16x8 af[4], bfr[4];
#pragma unroll
      for (int mf = 0; mf < 4; ++mf)
        af[mf] = *(const bf16x8*)&As[(wm + mf * 16 + l15) * 64 + kk + l4 * 8];
#pragma unroll
      for (int nf = 0; nf < 4; ++nf)
        bfr[nf] = *(const bf16x8*)&Bs[(wn + nf * 16 + l15) * 64 + kk + l4 * 8];
#pragma unroll
      for (int mf = 0; mf < 4; ++mf)
#pragma unroll
        for (int nf = 0; nf < 4; ++nf)
          acc[mf][nf] = __builtin_amdgcn_mfma_f32_16x16x32_bf16(af[mf], bfr[nf], acc[mf][nf], 0, 0, 0);
    }
  }
  float bias[4];
#pragma unroll
  for (int nf = 0; nf < 4; ++nf) bias[nf] = bqk[n0 + wn + nf * 16 + l15];
  __syncthreads();
  u16* Cs = smem;  // [128][136]
#pragma unroll
  for (int mf = 0; mf < 4; ++mf)
#pragma unroll
    for (int nf = 0; nf < 4; ++nf)
#pragma unroll
      for (int r = 0; r < 4; ++r)
        Cs[(wm + mf * 16 + l4 * 4 + r) * 136 + wn + nf * 16 + l15] =
            f2bf(acc[mf][nf][r] + bias[nf]);
  __syncthreads();
#pragma unroll
  for (int rr = 0; rr < 8; ++rr) {
    int row = rr * 16 + (tid >> 4), c8 = (tid & 15) * 8;
    *(u16x8*)&qk[(size_t)(m0 + row) * 1024 + n0 + c8] = *(const u16x8*)&Cs[row * 136 + c8];
  }
}

// ---------------- K2: per-(i,b) scores -> softmax -> head-mean -> w (bf16) ----------------
__global__ __launch_bounds__(256) void k_scores(
    const u16* __restrict__ qk, const unsigned char* __restrict__ mask,
    u16* __restrict__ wbuf) {
  const int i = blockIdx.x, b = blockIdx.y;
  __shared__ u16 smem[2 * 128 * 72];
  u16* qs = smem;
  u16* ks = smem + 128 * 72;
  const int tid = threadIdx.x, lane = tid & 63, wid = tid >> 6;
  const int l15 = lane & 15, l4 = lane >> 4;
  float wacc[2][8][4];
#pragma unroll
  for (int mf = 0; mf < 2; ++mf)
#pragma unroll
    for (int nf = 0; nf < 8; ++nf)
#pragma unroll
      for (int r = 0; r < 4; ++r) wacc[mf][nf][r] = 0.f;
  bool mk[8];
#pragma unroll
  for (int nf = 0; nf < 8; ++nf) mk[nf] = mask[i * 512 + b * 128 + nf * 16 + l15] != 0;
  const int arow = tid >> 3, acol = (tid & 7) * 8;
  const f32x4 fz = {0.f, 0.f, 0.f, 0.f};
  for (int h = 0; h < 8; ++h) {
    __syncthreads();
#pragma unroll
    for (int rr = 0; rr < 4; ++rr) {
      int row = rr * 32 + arow;
      int base = ((i * 128 + row) * 4 + b) * 1024 + h * 64 + acol;
      *(u16x8*)&qs[row * 72 + acol] = *(const u16x8*)&qk[base];
      *(u16x8*)&ks[row * 72 + acol] = *(const u16x8*)&qk[base + 512];
    }
    __syncthreads();
#pragma unroll
    for (int mf = 0; mf < 2; ++mf) {
      f32x4 sc[8];
#pragma unroll
      for (int nf = 0; nf < 8; ++nf) sc[nf] = fz;
#pragma unroll
      for (int kk = 0; kk < 64; kk += 32) {
        bf16x8 a = *(const bf16x8*)&qs[(wid * 32 + mf * 16 + l15) * 72 + kk + l4 * 8];
#pragma unroll
        for (int nf = 0; nf < 8; ++nf) {
          bf16x8 bb = *(const bf16x8*)&ks[(nf * 16 + l15) * 72 + kk + l4 * 8];
          sc[nf] = __builtin_amdgcn_mfma_f32_16x16x32_bf16(a, bb, sc[nf], 0, 0, 0);
        }
      }
#pragma unroll
      for (int r = 0; r < 4; ++r) {
        float mx = -3e38f;
#pragma unroll
        for (int nf = 0; nf < 8; ++nf) mx = fmaxf(mx, mk[nf] ? -3e38f : sc[nf][r]);
#pragma unroll
        for (int d = 1; d < 16; d <<= 1) mx = fmaxf(mx, __shfl_xor(mx, d, 64));
        float p[8], sum = 0.f;
#pragma unroll
        for (int nf = 0; nf < 8; ++nf) {
          p[nf] = mk[nf] ? 0.f : __expf(sc[nf][r] - mx);
          sum += p[nf];
        }
#pragma unroll
        for (int d = 1; d < 16; d <<= 1) sum += __shfl_xor(sum, d, 64);
        float inv = 0.125f / sum;
#pragma unroll
        for (int nf = 0; nf < 8; ++nf) wacc[mf][nf][r] += p[nf] * inv;
      }
    }
  }
#pragma unroll
  for (int mf = 0; mf < 2; ++mf)
#pragma unroll
    for (int nf = 0; nf < 8; ++nf)
#pragma unroll
      for (int r = 0; r < 4; ++r) {
        int t = wid * 32 + mf * 16 + l4 * 4 + r;
        wbuf[((i * 4 + b) * 128 + t) * 128 + nf * 16 + l15] = f2bf(wacc[mf][nf][r]);
      }
}

// ---------------- K3: x-mix  xT[h][t] = sum_s stT[h][s] * w[t][s], per (i,b,hc) ----------------
__global__ __launch_bounds__(256) void k_xmix(
    const u16* __restrict__ stT, const u16* __restrict__ wbuf,
    u16* __restrict__ xbuf) {
  const int i = blockIdx.x, b = blockIdx.y, hc = blockIdx.z;
  __shared__ u16 smem[2 * 128 * 136];
  u16* ST = smem;
  u16* WS = smem + 128 * 136;
  const int tid = threadIdx.x, lane = tid & 63, wid = tid >> 6;
  const int l15 = lane & 15, l4 = lane >> 4;
  const int wh = (wid >> 1) * 64, wt = (wid & 1) * 64;
  const f32x4 fz = {0.f, 0.f, 0.f, 0.f};
  f32x4 acc[4][4];
#pragma unroll
  for (int a = 0; a < 4; ++a)
#pragma unroll
    for (int c = 0; c < 4; ++c) acc[a][c] = fz;
  const int r16 = tid >> 4, c8 = (tid & 15) * 8;
#pragma unroll
  for (int rr = 0; rr < 8; ++rr) {
    int row = rr * 16 + r16;
    *(u16x8*)&ST[row * 136 + c8] =
        *(const u16x8*)&stT[((i * 4 + b) * 512 + hc * 128 + row) * 128 + c8];
    *(u16x8*)&WS[row * 136 + c8] =
        *(const u16x8*)&wbuf[((i * 4 + b) * 128 + row) * 128 + c8];
  }
  __syncthreads();
#pragma unroll
  for (int kk = 0; kk < 128; kk += 32) {
    bf16x8 af[4], bfr[4];
#pragma unroll
    for (int mf = 0; mf < 4; ++mf)
      af[mf] = *(const bf16x8*)&ST[(wh + mf * 16 + l15) * 136 + kk + l4 * 8];
#pragma unroll
    for (int nf = 0; nf < 4; ++nf)
      bfr[nf] = *(const bf16x8*)&WS[(wt + nf * 16 + l15) * 136 + kk + l4 * 8];
#pragma unroll
    for (int mf = 0; mf < 4; ++mf)
#pragma unroll
      for (int nf = 0; nf < 4; ++nf)
        acc[mf][nf] = __builtin_amdgcn_mfma_f32_16x16x32_bf16(af[mf], bfr[nf], acc[mf][nf], 0, 0, 0);
  }
  __syncthreads();
  u16* Cs = smem;  // [t][h] 128x136
#pragma unroll
  for (int mf = 0; mf < 4; ++mf)
#pragma unroll
    for (int nf = 0; nf < 4; ++nf) {
      int h0 = wh + mf * 16 + l4 * 4;
      int t = wt + nf * 16 + l15;
      u16x4 pk = { f2bf(acc[mf][nf][0]), f2bf(acc[mf][nf][1]),
                   f2bf(acc[mf][nf][2]), f2bf(acc[mf][nf][3]) };
      *(u16x4*)&Cs[t * 136 + h0] = pk;
    }
  __syncthreads();
#pragma unroll
  for (int rr = 0; rr < 8; ++rr) {
    int t = rr * 16 + r16;
    *(u16x8*)&xbuf[((i * 128 + t) * 4 + b) * 512 + hc * 128 + c8] =
        *(const u16x8*)&Cs[t * 136 + c8];
  }
}

// ---------------- K4: rel-mix, transpose fused ----------------
// per (t,b,hc): RT[h'][s] = bf16(relation[s][t][b][hc*128+h']) built via 4-chunk in-LDS
// transpose (T[32][136] scratch overlaid on WS); then acc[h'][i] = sum_s RT[h'][s]*WS[i][s].
// Replaces the separate k_transpose_rel kernel (net -134MB global traffic).
__global__ __launch_bounds__(256) void k_relmix(
    const float* __restrict__ relation, const u16* __restrict__ wbuf,
    u16* __restrict__ relbuf) {
  const int t = blockIdx.x, b = blockIdx.y, hc = blockIdx.z;
  __shared__ u16 smem[2 * 128 * 136];
  u16* RT = smem;              // [128][136] RT[h'][s]
  u16* WS = smem + 128 * 136;  // [128][136] WS[i][s]; T scratch overlays this
  u16* T = WS;                 // [32][136]
  const int tid = threadIdx.x, lane = tid & 63, wid = tid >> 6;
  const int l15 = lane & 15, l4 = lane >> 4;
  const int wh = (wid >> 1) * 64, wi = (wid & 1) * 64;
  const int sr = tid >> 3, hseg = (tid & 7) * 16;  // chunk-load mapping (32 s-rows x 128 h)
  const int th = tid >> 1, sseg = (tid & 1) * 16;  // scatter mapping (128 h x 32 s)
#pragma unroll
  for (int ch = 0; ch < 4; ++ch) {
    const int sbase = ch * 32;
    size_t gaddr = (((size_t)(sbase + sr) * 128 + t) * 4 + b) * 512 + hc * 128 + hseg;
    f32x4 v0 = *(const f32x4*)&relation[gaddr];
    f32x4 v1 = *(const f32x4*)&relation[gaddr + 4];
    f32x4 v2 = *(const f32x4*)&relation[gaddr + 8];
    f32x4 v3 = *(const f32x4*)&relation[gaddr + 12];
    __syncthreads();  // previous chunk's T readers done
    *(u16x8*)&T[sr * 136 + hseg] = pack8(v0, v1);
    *(u16x8*)&T[sr * 136 + hseg + 8] = pack8(v2, v3);
    __syncthreads();
    u16x8 c0, c1;
#pragma unroll
    for (int j = 0; j < 8; ++j) c0[j] = T[(sseg + j) * 136 + th];
#pragma unroll
    for (int j = 0; j < 8; ++j) c1[j] = T[(sseg + 8 + j) * 136 + th];
    *(u16x8*)&RT[th * 136 + sbase + sseg] = c0;
    *(u16x8*)&RT[th * 136 + sbase + sseg + 8] = c1;
  }
  __syncthreads();  // last chunk's T readers done before WS fill overwrites T
  const int r16 = tid >> 4, c8 = (tid & 15) * 8;
#pragma unroll
  for (int rr = 0; rr < 8; ++rr) {
    int row = rr * 16 + r16;
    *(u16x8*)&WS[row * 136 + c8] =
        *(const u16x8*)&wbuf[((row * 4 + b) * 128 + t) * 128 + c8];
  }
  __syncthreads();
  const f32x4 fz = {0.f, 0.f, 0.f, 0.f};
  f32x4 acc[4][4];
#pragma unroll
  for (int a = 0; a < 4; ++a)
#pragma unroll
    for (int c = 0; c < 4; ++c) acc[a][c] = fz;
#pragma unroll
  for (int kk = 0; kk < 128; kk += 32) {
    bf16x8 af[4], bfr[4];
#pragma unroll
    for (int mf = 0; mf < 4; ++mf)
      af[mf] = *(const bf16x8*)&RT[(wh + mf * 16 + l15) * 136 + kk + l4 * 8];
#pragma unroll
    for (int nf = 0; nf < 4; ++nf)
      bfr[nf] = *(const bf16x8*)&WS[(wi + nf * 16 + l15) * 136 + kk + l4 * 8];
#pragma unroll
    for (int mf = 0; mf < 4; ++mf)
#pragma unroll
      for (int nf = 0; nf < 4; ++nf)
        acc[mf][nf] = __builtin_amdgcn_mfma_f32_16x16x32_bf16(af[mf], bfr[nf], acc[mf][nf], 0, 0, 0);
  }
  __syncthreads();
  u16* Cs = smem;  // [i][h] 128x136
#pragma unroll
  for (int mf = 0; mf < 4; ++mf)
#pragma unroll
    for (int nf = 0; nf < 4; ++nf) {
      int h0 = wh + mf * 16 + l4 * 4;
      int ii = wi + nf * 16 + l15;
      u16x4 pk = { f2bf(acc[mf][nf][0]), f2bf(acc[mf][nf][1]),
                   f2bf(acc[mf][nf][2]), f2bf(acc[mf][nf][3]) };
      *(u16x4*)&Cs[ii * 136 + h0] = pk;
    }
  __syncthreads();
#pragma unroll
  for (int rr = 0; rr < 8; ++rr) {
    int ii = rr * 16 + r16;
    *(u16x8*)&relbuf[((ii * 128 + t) * 4 + b) * 512 + hc * 128 + c8] =
        *(const u16x8*)&Cs[ii * 136 + c8];
  }
}

// ---------------- K5a: out-proj GEMM (M=65536,N=512,K=1024) + bias + relu -> yb bf16 ----------------
// 1D grid 2048, XCD-chunked swizzle (same mechanism as k_qkproj, NT=4).
__global__ __launch_bounds__(256) void k_proj(
    const u16* __restrict__ xbuf, const u16* __restrict__ relbuf,
    const u16* __restrict__ wp, const float* __restrict__ bp,
    u16* __restrict__ yb) {
  const int flat = blockIdx.x;
  const int xcd = flat & 7, local = flat >> 3;          // local 0..255
  const int m0 = (xcd * 64 + (local >> 2)) * 128;
  const int n0 = (local & 3) * 128;
  __shared__ u16 smem[17408];  // As[128*64] | Bs[128*64]; epilogue Cs[128][136] overlays
  u16* As = smem;
  u16* Bs = smem + 8192;
  const int tid = threadIdx.x, lane = tid & 63, wid = tid >> 6;
  const int l15 = lane & 15, l4 = lane >> 4;
  const int wm = (wid >> 1) * 64, wn = (wid & 1) * 64;
  const int lr = lane >> 3, lc = (lane & 7) * 8;
  const f32x4 fz = {0.f, 0.f, 0.f, 0.f};
  f32x4 acc[4][4];
#pragma unroll
  for (int a = 0; a < 4; ++a)
#pragma unroll
    for (int c = 0; c < 4; ++c) acc[a][c] = fz;
  for (int k0 = 0; k0 < 1024; k0 += 64) {
    if (k0) __syncthreads();
    const u16* abase = (k0 < 512) ? xbuf + k0 : relbuf + (k0 - 512);
#pragma unroll
    for (int j = 0; j < 4; ++j) {
      int rb = wid * 32 + j * 8;
      gload16(&abase[(size_t)(m0 + rb + lr) * 512 + lc], &As[rb * 64]);
      gload16(&wp[(size_t)(n0 + rb + lr) * 1024 + k0 + lc], &Bs[rb * 64]);
    }
    __syncthreads();
#pragma unroll
    for (int kk = 0; kk < 64; kk += 32) {
      bf16x8 af[4], bfr[4];
#pragma unroll
      for (int mf = 0; mf < 4; ++mf)
        af[mf] = *(const bf16x8*)&As[(wm + mf * 16 + l15) * 64 + kk + l4 * 8];
#pragma unroll
      for (int nf = 0; nf < 4; ++nf)
        bfr[nf] = *(const bf16x8*)&Bs[(wn + nf * 16 + l15) * 64 + kk + l4 * 8];
#pragma unroll
      for (int mf = 0; mf < 4; ++mf)
#pragma unroll
        for (int nf = 0; nf < 4; ++nf)
          acc[mf][nf] = __builtin_amdgcn_mfma_f32_16x16x32_bf16(af[mf], bfr[nf], acc[mf][nf], 0, 0, 0);
    }
  }
  float bias[4];
#pragma unroll
  for (int nf = 0; nf < 4; ++nf) bias[nf] = bp[n0 + wn + nf * 16 + l15];
  __syncthreads();
  u16* Cs = smem;  // [128][136]
#pragma unroll
  for (int mf = 0; mf < 4; ++mf)
#pragma unroll
    for (int nf = 0; nf < 4; ++nf)
#pragma unroll
      for (int r = 0; r < 4; ++r)
        Cs[(wm + mf * 16 + l4 * 4 + r) * 136 + wn + nf * 16 + l15] =
            f2bf(fmaxf(acc[mf][nf][r] + bias[nf], 0.f));
  __syncthreads();
#pragma unroll
  for (int rr = 0; rr < 8; ++rr) {
    int row = rr * 16 + (tid >> 4), c8 = (tid & 15) * 8;
    *(u16x8*)&yb[(size_t)(m0 + row) * 512 + n0 + c8] = *(const u16x8*)&Cs[row * 136 + c8];
  }
}

// ---------------- K5b: residual + LayerNorm (memory-bound row pass) ----------------
__global__ __launch_bounds__(256) void k_ln(
    const u16* __restrict__ yb, const float* __restrict__ state,
    const float* __restrict__ gamma, const float* __restrict__ beta,
    float* __restrict__ out) {
  const int tid = threadIdx.x, lane = tid & 63, wid = tid >> 6;
  f32x4 g0 = *(const f32x4*)&gamma[lane * 8];
  f32x4 g1 = *(const f32x4*)&gamma[lane * 8 + 4];
  f32x4 be0 = *(const f32x4*)&beta[lane * 8];
  f32x4 be1 = *(const f32x4*)&beta[lane * 8 + 4];
  for (int row = blockIdx.x * 4 + wid; row < 65536; row += gridDim.x * 4) {
    size_t gbase = (size_t)row * 512 + lane * 8;
    u16x8 yv = *(const u16x8*)&yb[gbase];
    f32x4 s0 = *(const f32x4*)&state[gbase];
    f32x4 s1 = *(const f32x4*)&state[gbase + 4];
    float y[8];
#pragma unroll
    for (int j = 0; j < 4; ++j) y[j] = bf2f(yv[j]) + s0[j];
#pragma unroll
    for (int j = 0; j < 4; ++j) y[4 + j] = bf2f(yv[4 + j]) + s1[j];
    float sum = 0.f, sq = 0.f;
#pragma unroll
    for (int j = 0; j < 8; ++j) { sum += y[j]; sq += y[j] * y[j]; }
#pragma unroll
    for (int d = 1; d < 64; d <<= 1) { sum += __shfl_xor(sum, d, 64); sq += __shfl_xor(sq, d, 64); }
    float mu = sum * (1.f / 512.f);
    float var = sq * (1.f / 512.f) - mu * mu;
    float rs = rsqrtf(var + 1e-5f);
    f32x4 o0, o1;
#pragma unroll
    for (int j = 0; j < 4; ++j) o0[j] = g0[j] * (y[j] - mu) * rs + be0[j];
#pragma unroll
    for (int j = 0; j < 4; ++j) o1[j] = g1[j] * (y[4 + j] - mu) * rs + be1[j];
    *(f32x4*)&out[gbase] = o0;
    *(f32x4*)&out[gbase + 4] = o1;
  }
}

extern "C" void kernel_launch(void* const* d_in, const int* in_sizes, int n_in,
                              void* d_out, int out_size, void* d_ws, size_t ws_size,
                              hipStream_t stream) {
  const float* state = (const float*)d_in[0];
  const float* relation = (const float*)d_in[1];
  const unsigned char* mask = (const unsigned char*)d_in[2];
  const float* Wq = (const float*)d_in[4];
  const float* bq = (const float*)d_in[5];
  const float* Wk = (const float*)d_in[6];
  const float* bk = (const float*)d_in[7];
  const float* Wp = (const float*)d_in[8];
  const float* bp = (const float*)d_in[9];
  const float* gamma = (const float*)d_in[10];
  const float* beta = (const float*)d_in[11];
  float* out = (float*)d_out;
  char* ws = (char*)d_ws;

  // workspace layout (bytes); aliases (lifetimes disjoint):
  //   xbuf/relbuf alias qk (dead after k_scores)
  //   yb aliases stT (dead after k_xmix)
  //   stB lives where relT used to be (k_transpose_rel now fused away)
  u16* qk     = (u16*)(ws);                    // 134,217,728
  u16* xbuf   = (u16*)(ws);                    //  67,108,864 (alias qk lower half)
  u16* relbuf = (u16*)(ws + 67108864);         //  67,108,864 (alias qk upper half)
  u16* stT    = (u16*)(ws + 134217728);        //  67,108,864
  u16* yb     = (u16*)(ws + 134217728);        //  67,108,864 (alias stT)
  u16* stB    = (u16*)(ws + 201326592);        //  67,108,864
  u16* wbuf   = (u16*)(ws + 268435456);        //  16,777,216
  u16* wqk    = (u16*)(ws + 285212672);        //   1,048,576
  u16* wp     = (u16*)(ws + 286261248);        //   1,048,576
  float* bqk  = (float*)(ws + 287309824);      //       4,096

  k_prep<<<2048, 256, 0, stream>>>(Wq, Wk, bq, bk, Wp, wqk, wp, bqk);
  k_transpose_state<<<dim3(16, 4, 128), 256, 0, stream>>>(state, stT, stB);
  k_qkproj<<<4096, 256, 0, stream>>>(stB, wqk, bqk, qk);
  k_scores<<<dim3(128, 4), 256, 0, stream>>>(qk, mask, wbuf);
  k_xmix<<<dim3(128, 4, 4), 256, 0, stream>>>(stT, wbuf, xbuf);
  k_relmix<<<dim3(128, 4, 4), 256, 0, stream>>>(relation, wbuf, relbuf);
  k_proj<<<2048, 256, 0, stream>>>(xbuf, relbuf, wp, bp, yb);
  k_ln<<<2048, 256, 0, stream>>>(yb, state, gamma, beta, out);
}

// Round 10
// 416.597 us; speedup vs baseline: 1.2559x; 1.0600x over previous
//
#include <hip/hip_runtime.h>

typedef unsigned short u16;
typedef __attribute__((ext_vector_type(4))) unsigned short u16x4;
typedef __attribute__((ext_vector_type(8))) unsigned short u16x8;
typedef __attribute__((ext_vector_type(8))) short bf16x8;
typedef __attribute__((ext_vector_type(4))) float f32x4;

__device__ __forceinline__ u16 f2bf(float f) {
  union { float f; unsigned u; } v; v.f = f;
  unsigned r = v.u + 0x7fffu + ((v.u >> 16) & 1u);
  return (u16)(r >> 16);
}
__device__ __forceinline__ float bf2f(u16 u) {
  union { unsigned u; float f; } v; v.u = ((unsigned)u) << 16;
  return v.f;
}
__device__ __forceinline__ u16x8 pack8(f32x4 a, f32x4 b) {
  u16x8 r = { f2bf(a.x), f2bf(a.y), f2bf(a.z), f2bf(a.w),
              f2bf(b.x), f2bf(b.y), f2bf(b.z), f2bf(b.w) };
  return r;
}
// async global->LDS, 16B per lane; LDS dest = wave-uniform base + lane*16
__device__ __forceinline__ void gload16(const void* g, void* l) {
  __builtin_amdgcn_global_load_lds(
      (const __attribute__((address_space(1))) unsigned int*)g,
      (__attribute__((address_space(3))) unsigned int*)l, 16, 0, 0);
}

// ---------------- K0: weight prep (scale folded into Wq, bq) ----------------
__global__ __launch_bounds__(256) void k_prep(
    const float* __restrict__ Wq, const float* __restrict__ Wk,
    const float* __restrict__ bq, const float* __restrict__ bk,
    const float* __restrict__ Wp,
    u16* __restrict__ wqk, u16* __restrict__ wp, float* __restrict__ bqk) {
  int idx = blockIdx.x * 256 + threadIdx.x;
  if (idx < 524288) {
    int o = idx >> 9, hh = idx & 511;
    wqk[idx] = f2bf((o < 512) ? Wq[o * 512 + hh] * 0.125f : Wk[(o - 512) * 512 + hh]);
    wp[idx] = f2bf(Wp[idx]);
  }
  if (idx < 1024) bqk[idx] = (idx < 512) ? bq[idx] * 0.125f : bk[idx - 512];
}

// ---------------- KT1: state (i,s,b,h) -> stT bf16 [(i,b,h)][s]  AND  stB bf16 flat copy ----------------
__global__ __launch_bounds__(256) void k_transpose_state(
    const float* __restrict__ src, u16* __restrict__ dst, u16* __restrict__ stB) {
  const int i = blockIdx.z, b = blockIdx.y;
  const int s0 = (blockIdx.x & 1) * 64, h0 = (blockIdx.x >> 1) * 64;
  __shared__ u16 T[64][72];
  const int tid = threadIdx.x;
  const int ls = tid >> 4, lh = (tid & 15) * 4;
#pragma unroll
  for (int rr = 0; rr < 4; ++rr) {
    int s = rr * 16 + ls;
    size_t flat = ((size_t)(i * 128 + s0 + s) * 4 + b) * 512 + h0 + lh;
    f32x4 v = *(const f32x4*)&src[flat];
    u16x4 w4 = { f2bf(v.x), f2bf(v.y), f2bf(v.z), f2bf(v.w) };
    *(u16x4*)&T[s][lh] = w4;
    *(u16x4*)&stB[flat] = w4;
  }
  __syncthreads();
#pragma unroll
  for (int it = 0; it < 2; ++it) {
    int work = it * 256 + tid;
    int hh = work >> 3, sg = (work & 7) * 8;
    u16x8 o;
#pragma unroll
    for (int j = 0; j < 8; ++j) o[j] = T[sg + j][hh];
    *(u16x8*)&dst[((i * 4 + b) * 512 + h0 + hh) * 128 + s0 + sg] = o;
  }
}

// ---------------- K1: q,k projection GEMM (M=65536, N=1024, K=512), bf16 in/out ----------------
// XCD-chunked swizzle (r9: FETCH 264->43MB). This round: both-sides XOR bank swizzle —
// LDS linear (gload_lds requirement), global SOURCE per-lane chunk pre-swizzled
// ((lane&7)^(lane>>3)), reads XOR chunk with row&7. Kills the 16-way conflict of
// 128B-stride ds_read_b128 (r9: 2.57e7 conflict cycles ~ 34% of kernel).
__global__ __launch_bounds__(256) void k_qkproj(
    const u16* __restrict__ stB, const u16* __restrict__ wqk,
    const float* __restrict__ bqk, u16* __restrict__ qk) {
  const int flat = blockIdx.x;
  const int xcd = flat & 7, local = flat >> 3;          // local 0..511
  const int m0 = (xcd * 64 + (local >> 3)) * 128;       // 512 m-tiles, 64 per XCD
  const int n0 = (local & 7) * 128;                     // 8 n-tiles
  __shared__ u16 smem[17408];  // As[128*64] | Bs[128*64]; epilogue Cs[128][136] overlays
  u16* As = smem;
  u16* Bs = smem + 8192;
  const int tid = threadIdx.x, lane = tid & 63, wid = tid >> 6;
  const int l15 = lane & 15, l4 = lane >> 4;
  const int wm = (wid >> 1) * 64, wn = (wid & 1) * 64;
  const int lr = lane >> 3;                       // staging row-sub 0..7
  const int lcs = ((lane & 7) ^ lr) * 8;          // swizzled source col (u16)
  const int s7 = l15 & 7;                         // read-side row&7
  const f32x4 fz = {0.f, 0.f, 0.f, 0.f};
  f32x4 acc[4][4];
#pragma unroll
  for (int a = 0; a < 4; ++a)
#pragma unroll
    for (int c = 0; c < 4; ++c) acc[a][c] = fz;
  for (int k0 = 0; k0 < 512; k0 += 64) {
    if (k0) __syncthreads();
#pragma unroll
    for (int j = 0; j < 4; ++j) {
      int rb = wid * 32 + j * 8;  // wave-uniform row base
      gload16(&stB[(size_t)(m0 + rb + lr) * 512 + k0 + lcs], &As[rb * 64]);
      gload16(&wqk[(size_t)(n0 + rb + lr) * 512 + k0 + lcs], &Bs[rb * 64]);
    }
    __syncthreads();  // drains vmcnt(0) -> staged data visible
#pragma unroll
    for (int kk = 0; kk < 64; kk += 32) {
      const int cshift = (((kk >> 3) + l4) ^ s7) * 8;  // swizzled read col (u16)
      bf16x8 af[4], bfr[4];
#pragma unroll
      for (int mf = 0; mf < 4; ++mf)
        af[mf] = *(const bf16x8*)&As[(wm + mf * 16 + l15) * 64 + cshift];
#pragma unroll
      for (int nf = 0; nf < 4; ++nf)
        bfr[nf] = *(const bf16x8*)&Bs[(wn + nf * 16 + l15) * 64 + cshift];
#pragma unroll
      for (int mf = 0; mf < 4; ++mf)
#pragma unroll
        for (int nf = 0; nf < 4; ++nf)
          acc[mf][nf] = __builtin_amdgcn_mfma_f32_16x16x32_bf16(af[mf], bfr[nf], acc[mf][nf], 0, 0, 0);
    }
  }
  float bias[4];
#pragma unroll
  for (int nf = 0; nf < 4; ++nf) bias[nf] = bqk[n0 + wn + nf * 16 + l15];
  __syncthreads();
  u16* Cs = smem;  // [128][136]
#pragma unroll
  for (int mf = 0; mf < 4; ++mf)
#pragma unroll
    for (int nf = 0; nf < 4; ++nf)
#pragma unroll
      for (int r = 0; r < 4; ++r)
        Cs[(wm + mf * 16 + l4 * 4 + r) * 136 + wn + nf * 16 + l15] =
            f2bf(acc[mf][nf][r] + bias[nf]);
  __syncthreads();
#pragma unroll
  for (int rr = 0; rr < 8; ++rr) {
    int row = rr * 16 + (tid >> 4), c8 = (tid & 15) * 8;
    *(u16x8*)&qk[(size_t)(m0 + row) * 1024 + n0 + c8] = *(const u16x8*)&Cs[row * 136 + c8];
  }
}

// ---------------- K2: per-(i,b) scores -> softmax -> head-mean -> w (bf16) ----------------
__global__ __launch_bounds__(256) void k_scores(
    const u16* __restrict__ qk, const unsigned char* __restrict__ mask,
    u16* __restrict__ wbuf) {
  const int i = blockIdx.x, b = blockIdx.y;
  __shared__ u16 smem[2 * 128 * 72];
  u16* qs = smem;
  u16* ks = smem + 128 * 72;
  const int tid = threadIdx.x, lane = tid & 63, wid = tid >> 6;
  const int l15 = lane & 15, l4 = lane >> 4;
  float wacc[2][8][4];
#pragma unroll
  for (int mf = 0; mf < 2; ++mf)
#pragma unroll
    for (int nf = 0; nf < 8; ++nf)
#pragma unroll
      for (int r = 0; r < 4; ++r) wacc[mf][nf][r] = 0.f;
  bool mk[8];
#pragma unroll
  for (int nf = 0; nf < 8; ++nf) mk[nf] = mask[i * 512 + b * 128 + nf * 16 + l15] != 0;
  const int arow = tid >> 3, acol = (tid & 7) * 8;
  const f32x4 fz = {0.f, 0.f, 0.f, 0.f};
  for (int h = 0; h < 8; ++h) {
    __syncthreads();
#pragma unroll
    for (int rr = 0; rr < 4; ++rr) {
      int row = rr * 32 + arow;
      int base = ((i * 128 + row) * 4 + b) * 1024 + h * 64 + acol;
      *(u16x8*)&qs[row * 72 + acol] = *(const u16x8*)&qk[base];
      *(u16x8*)&ks[row * 72 + acol] = *(const u16x8*)&qk[base + 512];
    }
    __syncthreads();
#pragma unroll
    for (int mf = 0; mf < 2; ++mf) {
      f32x4 sc[8];
#pragma unroll
      for (int nf = 0; nf < 8; ++nf) sc[nf] = fz;
#pragma unroll
      for (int kk = 0; kk < 64; kk += 32) {
        bf16x8 a = *(const bf16x8*)&qs[(wid * 32 + mf * 16 + l15) * 72 + kk + l4 * 8];
#pragma unroll
        for (int nf = 0; nf < 8; ++nf) {
          bf16x8 bb = *(const bf16x8*)&ks[(nf * 16 + l15) * 72 + kk + l4 * 8];
          sc[nf] = __builtin_amdgcn_mfma_f32_16x16x32_bf16(a, bb, sc[nf], 0, 0, 0);
        }
      }
#pragma unroll
      for (int r = 0; r < 4; ++r) {
        float mx = -3e38f;
#pragma unroll
        for (int nf = 0; nf < 8; ++nf) mx = fmaxf(mx, mk[nf] ? -3e38f : sc[nf][r]);
#pragma unroll
        for (int d = 1; d < 16; d <<= 1) mx = fmaxf(mx, __shfl_xor(mx, d, 64));
        float p[8], sum = 0.f;
#pragma unroll
        for (int nf = 0; nf < 8; ++nf) {
          p[nf] = mk[nf] ? 0.f : __expf(sc[nf][r] - mx);
          sum += p[nf];
        }
#pragma unroll
        for (int d = 1; d < 16; d <<= 1) sum += __shfl_xor(sum, d, 64);
        float inv = 0.125f / sum;
#pragma unroll
        for (int nf = 0; nf < 8; ++nf) wacc[mf][nf][r] += p[nf] * inv;
      }
    }
  }
#pragma unroll
  for (int mf = 0; mf < 2; ++mf)
#pragma unroll
    for (int nf = 0; nf < 8; ++nf)
#pragma unroll
      for (int r = 0; r < 4; ++r) {
        int t = wid * 32 + mf * 16 + l4 * 4 + r;
        wbuf[((i * 4 + b) * 128 + t) * 128 + nf * 16 + l15] = f2bf(wacc[mf][nf][r]);
      }
}

// ---------------- K3: x-mix  xT[h][t] = sum_s stT[h][s] * w[t][s], per (i,b,hc) ----------------
__global__ __launch_bounds__(256) void k_xmix(
    const u16* __restrict__ stT, const u16* __restrict__ wbuf,
    u16* __restrict__ xbuf) {
  const int i = blockIdx.x, b = blockIdx.y, hc = blockIdx.z;
  __shared__ u16 smem[2 * 128 * 136];
  u16* ST = smem;
  u16* WS = smem + 128 * 136;
  const int tid = threadIdx.x, lane = tid & 63, wid = tid >> 6;
  const int l15 = lane & 15, l4 = lane >> 4;
  const int wh = (wid >> 1) * 64, wt = (wid & 1) * 64;
  const f32x4 fz = {0.f, 0.f, 0.f, 0.f};
  f32x4 acc[4][4];
#pragma unroll
  for (int a = 0; a < 4; ++a)
#pragma unroll
    for (int c = 0; c < 4; ++c) acc[a][c] = fz;
  const int r16 = tid >> 4, c8 = (tid & 15) * 8;
#pragma unroll
  for (int rr = 0; rr < 8; ++rr) {
    int row = rr * 16 + r16;
    *(u16x8*)&ST[row * 136 + c8] =
        *(const u16x8*)&stT[((i * 4 + b) * 512 + hc * 128 + row) * 128 + c8];
    *(u16x8*)&WS[row * 136 + c8] =
        *(const u16x8*)&wbuf[((i * 4 + b) * 128 + row) * 128 + c8];
  }
  __syncthreads();
#pragma unroll
  for (int kk = 0; kk < 128; kk += 32) {
    bf16x8 af[4], bfr[4];
#pragma unroll
    for (int mf = 0; mf < 4; ++mf)
      af[mf] = *(const bf16x8*)&ST[(wh + mf * 16 + l15) * 136 + kk + l4 * 8];
#pragma unroll
    for (int nf = 0; nf < 4; ++nf)
      bfr[nf] = *(const bf16x8*)&WS[(wt + nf * 16 + l15) * 136 + kk + l4 * 8];
#pragma unroll
    for (int mf = 0; mf < 4; ++mf)
#pragma unroll
      for (int nf = 0; nf < 4; ++nf)
        acc[mf][nf] = __builtin_amdgcn_mfma_f32_16x16x32_bf16(af[mf], bfr[nf], acc[mf][nf], 0, 0, 0);
  }
  __syncthreads();
  u16* Cs = smem;  // [t][h] 128x136
#pragma unroll
  for (int mf = 0; mf < 4; ++mf)
#pragma unroll
    for (int nf = 0; nf < 4; ++nf) {
      int h0 = wh + mf * 16 + l4 * 4;
      int t = wt + nf * 16 + l15;
      u16x4 pk = { f2bf(acc[mf][nf][0]), f2bf(acc[mf][nf][1]),
                   f2bf(acc[mf][nf][2]), f2bf(acc[mf][nf][3]) };
      *(u16x4*)&Cs[t * 136 + h0] = pk;
    }
  __syncthreads();
#pragma unroll
  for (int rr = 0; rr < 8; ++rr) {
    int t = rr * 16 + r16;
    *(u16x8*)&xbuf[((i * 128 + t) * 4 + b) * 512 + hc * 128 + c8] =
        *(const u16x8*)&Cs[t * 136 + c8];
  }
}

// ---------------- K4: rel-mix, transpose fused ----------------
__global__ __launch_bounds__(256) void k_relmix(
    const float* __restrict__ relation, const u16* __restrict__ wbuf,
    u16* __restrict__ relbuf) {
  const int t = blockIdx.x, b = blockIdx.y, hc = blockIdx.z;
  __shared__ u16 smem[2 * 128 * 136];
  u16* RT = smem;              // [128][136] RT[h'][s]
  u16* WS = smem + 128 * 136;  // [128][136] WS[i][s]; T scratch overlays this
  u16* T = WS;                 // [32][136]
  const int tid = threadIdx.x, lane = tid & 63, wid = tid >> 6;
  const int l15 = lane & 15, l4 = lane >> 4;
  const int wh = (wid >> 1) * 64, wi = (wid & 1) * 64;
  const int sr = tid >> 3, hseg = (tid & 7) * 16;  // chunk-load mapping (32 s-rows x 128 h)
  const int th = tid >> 1, sseg = (tid & 1) * 16;  // scatter mapping (128 h x 32 s)
#pragma unroll
  for (int ch = 0; ch < 4; ++ch) {
    const int sbase = ch * 32;
    size_t gaddr = (((size_t)(sbase + sr) * 128 + t) * 4 + b) * 512 + hc * 128 + hseg;
    f32x4 v0 = *(const f32x4*)&relation[gaddr];
    f32x4 v1 = *(const f32x4*)&relation[gaddr + 4];
    f32x4 v2 = *(const f32x4*)&relation[gaddr + 8];
    f32x4 v3 = *(const f32x4*)&relation[gaddr + 12];
    __syncthreads();  // previous chunk's T readers done
    *(u16x8*)&T[sr * 136 + hseg] = pack8(v0, v1);
    *(u16x8*)&T[sr * 136 + hseg + 8] = pack8(v2, v3);
    __syncthreads();
    u16x8 c0, c1;
#pragma unroll
    for (int j = 0; j < 8; ++j) c0[j] = T[(sseg + j) * 136 + th];
#pragma unroll
    for (int j = 0; j < 8; ++j) c1[j] = T[(sseg + 8 + j) * 136 + th];
    *(u16x8*)&RT[th * 136 + sbase + sseg] = c0;
    *(u16x8*)&RT[th * 136 + sbase + sseg + 8] = c1;
  }
  __syncthreads();  // last chunk's T readers done before WS fill overwrites T
  const int r16 = tid >> 4, c8 = (tid & 15) * 8;
#pragma unroll
  for (int rr = 0; rr < 8; ++rr) {
    int row = rr * 16 + r16;
    *(u16x8*)&WS[row * 136 + c8] =
        *(const u16x8*)&wbuf[((row * 4 + b) * 128 + t) * 128 + c8];
  }
  __syncthreads();
  const f32x4 fz = {0.f, 0.f, 0.f, 0.f};
  f32x4 acc[4][4];
#pragma unroll
  for (int a = 0; a < 4; ++a)
#pragma unroll
    for (int c = 0; c < 4; ++c) acc[a][c] = fz;
#pragma unroll
  for (int kk = 0; kk < 128; kk += 32) {
    bf16x8 af[4], bfr[4];
#pragma unroll
    for (int mf = 0; mf < 4; ++mf)
      af[mf] = *(const bf16x8*)&RT[(wh + mf * 16 + l15) * 136 + kk + l4 * 8];
#pragma unroll
    for (int nf = 0; nf < 4; ++nf)
      bfr[nf] = *(const bf16x8*)&WS[(wi + nf * 16 + l15) * 136 + kk + l4 * 8];
#pragma unroll
    for (int mf = 0; mf < 4; ++mf)
#pragma unroll
      for (int nf = 0; nf < 4; ++nf)
        acc[mf][nf] = __builtin_amdgcn_mfma_f32_16x16x32_bf16(af[mf], bfr[nf], acc[mf][nf], 0, 0, 0);
  }
  __syncthreads();
  u16* Cs = smem;  // [i][h] 128x136
#pragma unroll
  for (int mf = 0; mf < 4; ++mf)
#pragma unroll
    for (int nf = 0; nf < 4; ++nf) {
      int h0 = wh + mf * 16 + l4 * 4;
      int ii = wi + nf * 16 + l15;
      u16x4 pk = { f2bf(acc[mf][nf][0]), f2bf(acc[mf][nf][1]),
                   f2bf(acc[mf][nf][2]), f2bf(acc[mf][nf][3]) };
      *(u16x4*)&Cs[ii * 136 + h0] = pk;
    }
  __syncthreads();
#pragma unroll
  for (int rr = 0; rr < 8; ++rr) {
    int ii = rr * 16 + r16;
    *(u16x8*)&relbuf[((ii * 128 + t) * 4 + b) * 512 + hc * 128 + c8] =
        *(const u16x8*)&Cs[ii * 136 + c8];
  }
}

// ---------------- K5a: out-proj GEMM (M=65536,N=512,K=1024) + bias + relu -> yb bf16 ----------------
// XCD-chunked swizzle + both-sides XOR bank swizzle (same as k_qkproj).
__global__ __launch_bounds__(256) void k_proj(
    const u16* __restrict__ xbuf, const u16* __restrict__ relbuf,
    const u16* __restrict__ wp, const float* __restrict__ bp,
    u16* __restrict__ yb) {
  const int flat = blockIdx.x;
  const int xcd = flat & 7, local = flat >> 3;          // local 0..255
  const int m0 = (xcd * 64 + (local >> 2)) * 128;
  const int n0 = (local & 3) * 128;
  __shared__ u16 smem[17408];
  u16* As = smem;
  u16* Bs = smem + 8192;
  const int tid = threadIdx.x, lane = tid & 63, wid = tid >> 6;
  const int l15 = lane & 15, l4 = lane >> 4;
  const int wm = (wid >> 1) * 64, wn = (wid & 1) * 64;
  const int lr = lane >> 3;
  const int lcs = ((lane & 7) ^ lr) * 8;          // swizzled source col (u16)
  const int s7 = l15 & 7;
  const f32x4 fz = {0.f, 0.f, 0.f, 0.f};
  f32x4 acc[4][4];
#pragma unroll
  for (int a = 0; a < 4; ++a)
#pragma unroll
    for (int c = 0; c < 4; ++c) acc[a][c] = fz;
  for (int k0 = 0; k0 < 1024; k0 += 64) {
    if (k0) __syncthreads();
    const u16* abase = (k0 < 512) ? xbuf + k0 : relbuf + (k0 - 512);
#pragma unroll
    for (int j = 0; j < 4; ++j) {
      int rb = wid * 32 + j * 8;
      gload16(&abase[(size_t)(m0 + rb + lr) * 512 + lcs], &As[rb * 64]);
      gload16(&wp[(size_t)(n0 + rb + lr) * 1024 + k0 + lcs], &Bs[rb * 64]);
    }
    __syncthreads();
#pragma unroll
    for (int kk = 0; kk < 64; kk += 32) {
      const int cshift = (((kk >> 3) + l4) ^ s7) * 8;
      bf16x8 af[4], bfr[4];
#pragma unroll
      for (int mf = 0; mf < 4; ++mf)
        af[mf] = *(const bf16x8*)&As[(wm + mf * 16 + l15) * 64 + cshift];
#pragma unroll
      for (int nf = 0; nf < 4; ++nf)
        bfr[nf] = *(const bf16x8*)&Bs[(wn + nf * 16 + l15) * 64 + cshift];
#pragma unroll
      for (int mf = 0; mf < 4; ++mf)
#pragma unroll
        for (int nf = 0; nf < 4; ++nf)
          acc[mf][nf] = __builtin_amdgcn_mfma_f32_16x16x32_bf16(af[mf], bfr[nf], acc[mf][nf], 0, 0, 0);
    }
  }
  float bias[4];
#pragma unroll
  for (int nf = 0; nf < 4; ++nf) bias[nf] = bp[n0 + wn + nf * 16 + l15];
  __syncthreads();
  u16* Cs = smem;  // [128][136]
#pragma unroll
  for (int mf = 0; mf < 4; ++mf)
#pragma unroll
    for (int nf = 0; nf < 4; ++nf)
#pragma unroll
      for (int r = 0; r < 4; ++r)
        Cs[(wm + mf * 16 + l4 * 4 + r) * 136 + wn + nf * 16 + l15] =
            f2bf(fmaxf(acc[mf][nf][r] + bias[nf], 0.f));
  __syncthreads();
#pragma unroll
  for (int rr = 0; rr < 8; ++rr) {
    int row = rr * 16 + (tid >> 4), c8 = (tid & 15) * 8;
    *(u16x8*)&yb[(size_t)(m0 + row) * 512 + n0 + c8] = *(const u16x8*)&Cs[row * 136 + c8];
  }
}

// ---------------- K5b: residual + LayerNorm (memory-bound row pass) ----------------
__global__ __launch_bounds__(256) void k_ln(
    const u16* __restrict__ yb, const float* __restrict__ state,
    const float* __restrict__ gamma, const float* __restrict__ beta,
    float* __restrict__ out) {
  const int tid = threadIdx.x, lane = tid & 63, wid = tid >> 6;
  f32x4 g0 = *(const f32x4*)&gamma[lane * 8];
  f32x4 g1 = *(const f32x4*)&gamma[lane * 8 + 4];
  f32x4 be0 = *(const f32x4*)&beta[lane * 8];
  f32x4 be1 = *(const f32x4*)&beta[lane * 8 + 4];
  for (int row = blockIdx.x * 4 + wid; row < 65536; row += gridDim.x * 4) {
    size_t gbase = (size_t)row * 512 + lane * 8;
    u16x8 yv = *(const u16x8*)&yb[gbase];
    f32x4 s0 = *(const f32x4*)&state[gbase];
    f32x4 s1 = *(const f32x4*)&state[gbase + 4];
    float y[8];
#pragma unroll
    for (int j = 0; j < 4; ++j) y[j] = bf2f(yv[j]) + s0[j];
#pragma unroll
    for (int j = 0; j < 4; ++j) y[4 + j] = bf2f(yv[4 + j]) + s1[j];
    float sum = 0.f, sq = 0.f;
#pragma unroll
    for (int j = 0; j < 8; ++j) { sum += y[j]; sq += y[j] * y[j]; }
#pragma unroll
    for (int d = 1; d < 64; d <<= 1) { sum += __shfl_xor(sum, d, 64); sq += __shfl_xor(sq, d, 64); }
    float mu = sum * (1.f / 512.f);
    float var = sq * (1.f / 512.f) - mu * mu;
    float rs = rsqrtf(var + 1e-5f);
    f32x4 o0, o1;
#pragma unroll
    for (int j = 0; j < 4; ++j) o0[j] = g0[j] * (y[j] - mu) * rs + be0[j];
#pragma unroll
    for (int j = 0; j < 4; ++j) o1[j] = g1[j] * (y[4 + j] - mu) * rs + be1[j];
    *(f32x4*)&out[gbase] = o0;
    *(f32x4*)&out[gbase + 4] = o1;
  }
}

extern "C" void kernel_launch(void* const* d_in, const int* in_sizes, int n_in,
                              void* d_out, int out_size, void* d_ws, size_t ws_size,
                              hipStream_t stream) {
  const float* state = (const float*)d_in[0];
  const float* relation = (const float*)d_in[1];
  const unsigned char* mask = (const unsigned char*)d_in[2];
  const float* Wq = (const float*)d_in[4];
  const float* bq = (const float*)d_in[5];
  const float* Wk = (const float*)d_in[6];
  const float* bk = (const float*)d_in[7];
  const float* Wp = (const float*)d_in[8];
  const float* bp = (const float*)d_in[9];
  const float* gamma = (const float*)d_in[10];
  const float* beta = (const float*)d_in[11];
  float* out = (float*)d_out;
  char* ws = (char*)d_ws;

  u16* qk     = (u16*)(ws);                    // 134,217,728
  u16* xbuf   = (u16*)(ws);                    //  67,108,864 (alias qk lower half)
  u16* relbuf = (u16*)(ws + 67108864);         //  67,108,864 (alias qk upper half)
  u16* stT    = (u16*)(ws + 134217728);        //  67,108,864
  u16* yb     = (u16*)(ws + 134217728);        //  67,108,864 (alias stT)
  u16* stB    = (u16*)(ws + 201326592);        //  67,108,864
  u16* wbuf   = (u16*)(ws + 268435456);        //  16,777,216
  u16* wqk    = (u16*)(ws + 285212672);        //   1,048,576
  u16* wp     = (u16*)(ws + 286261248);        //   1,048,576
  float* bqk  = (float*)(ws + 287309824);      //       4,096

  k_prep<<<2048, 256, 0, stream>>>(Wq, Wk, bq, bk, Wp, wqk, wp, bqk);
  k_transpose_state<<<dim3(16, 4, 128), 256, 0, stream>>>(state, stT, stB);
  k_qkproj<<<4096, 256, 0, stream>>>(stB, wqk, bqk, qk);
  k_scores<<<dim3(128, 4), 256, 0, stream>>>(qk, mask, wbuf);
  k_xmix<<<dim3(128, 4, 4), 256, 0, stream>>>(stT, wbuf, xbuf);
  k_relmix<<<dim3(128, 4, 4), 256, 0, stream>>>(relation, wbuf, relbuf);
  k_proj<<<2048, 256, 0, stream>>>(xbuf, relbuf, wp, bp, yb);
  k_ln<<<2048, 256, 0, stream>>>(yb, state, gamma, beta, out);
}

// Round 13
// 377.387 us; speedup vs baseline: 1.3864x; 1.1039x over previous
//
#include <hip/hip_runtime.h>

typedef unsigned short u16;
typedef __attribute__((ext_vector_type(4))) unsigned short u16x4;
typedef __attribute__((ext_vector_type(8))) unsigned short u16x8;
typedef __attribute__((ext_vector_type(8))) short bf16x8;
typedef __attribute__((ext_vector_type(4))) float f32x4;

__device__ __forceinline__ u16 f2bf(float f) {
  union { float f; unsigned u; } v; v.f = f;
  unsigned r = v.u + 0x7fffu + ((v.u >> 16) & 1u);
  return (u16)(r >> 16);
}
__device__ __forceinline__ float bf2f(u16 u) {
  union { unsigned u; float f; } v; v.u = ((unsigned)u) << 16;
  return v.f;
}
__device__ __forceinline__ u16x8 pack8(f32x4 a, f32x4 b) {
  u16x8 r = { f2bf(a.x), f2bf(a.y), f2bf(a.z), f2bf(a.w),
              f2bf(b.x), f2bf(b.y), f2bf(b.z), f2bf(b.w) };
  return r;
}
// async global->LDS, 16B per lane; LDS dest = wave-uniform base + lane*16
__device__ __forceinline__ void gload16(const void* g, void* l) {
  __builtin_amdgcn_global_load_lds(
      (const __attribute__((address_space(1))) unsigned int*)g,
      (__attribute__((address_space(3))) unsigned int*)l, 16, 0, 0);
}

// ---------------- K0: weight prep (scale folded into Wq, bq) ----------------
__global__ __launch_bounds__(256) void k_prep(
    const float* __restrict__ Wq, const float* __restrict__ Wk,
    const float* __restrict__ bq, const float* __restrict__ bk,
    const float* __restrict__ Wp,
    u16* __restrict__ wqk, u16* __restrict__ wp, float* __restrict__ bqk) {
  int idx = blockIdx.x * 256 + threadIdx.x;
  if (idx < 524288) {
    int o = idx >> 9, hh = idx & 511;
    wqk[idx] = f2bf((o < 512) ? Wq[o * 512 + hh] * 0.125f : Wk[(o - 512) * 512 + hh]);
    wp[idx] = f2bf(Wp[idx]);
  }
  if (idx < 1024) bqk[idx] = (idx < 512) ? bq[idx] * 0.125f : bk[idx - 512];
}

// ---------------- K-cast: state fp32 -> stB bf16 (flat, one pass) ----------------
// Replaces k_transpose_state: stT is gone (k_xmix now transposes in-LDS like k_relmix).
__global__ __launch_bounds__(256) void k_cast(
    const float* __restrict__ src, u16* __restrict__ dst) {
  size_t idx = ((size_t)blockIdx.x * 256 + threadIdx.x) * 8;  // 16384 blocks x 256 x 8 = 33.5M
  f32x4 v0 = *(const f32x4*)&src[idx];
  f32x4 v1 = *(const f32x4*)&src[idx + 4];
  *(u16x8*)&dst[idx] = pack8(v0, v1);
}

// ---------------- K1: q,k projection GEMM (M=65536, N=1024, K=512), bf16 in/out ----------------
// XCD-chunked block swizzle (r9: FETCH 264->43MB) + both-sides XOR bank swizzle
// (r10: conflicts 2.57e7->5e5). Now at the 2-barrier-structure latency floor (~25% MfmaUtil).
__global__ __launch_bounds__(256) void k_qkproj(
    const u16* __restrict__ stB, const u16* __restrict__ wqk,
    const float* __restrict__ bqk, u16* __restrict__ qk) {
  const int flat = blockIdx.x;
  const int xcd = flat & 7, local = flat >> 3;          // local 0..511
  const int m0 = (xcd * 64 + (local >> 3)) * 128;       // 512 m-tiles, 64 per XCD
  const int n0 = (local & 7) * 128;                     // 8 n-tiles
  __shared__ u16 smem[17408];  // As[128*64] | Bs[128*64]; epilogue Cs[128][136] overlays
  u16* As = smem;
  u16* Bs = smem + 8192;
  const int tid = threadIdx.x, lane = tid & 63, wid = tid >> 6;
  const int l15 = lane & 15, l4 = lane >> 4;
  const int wm = (wid >> 1) * 64, wn = (wid & 1) * 64;
  const int lr = lane >> 3;                       // staging row-sub 0..7
  const int lcs = ((lane & 7) ^ lr) * 8;          // swizzled source col (u16)
  const int s7 = l15 & 7;                         // read-side row&7
  const f32x4 fz = {0.f, 0.f, 0.f, 0.f};
  f32x4 acc[4][4];
#pragma unroll
  for (int a = 0; a < 4; ++a)
#pragma unroll
    for (int c = 0; c < 4; ++c) acc[a][c] = fz;
  for (int k0 = 0; k0 < 512; k0 += 64) {
    if (k0) __syncthreads();
#pragma unroll
    for (int j = 0; j < 4; ++j) {
      int rb = wid * 32 + j * 8;  // wave-uniform row base
      gload16(&stB[(size_t)(m0 + rb + lr) * 512 + k0 + lcs], &As[rb * 64]);
      gload16(&wqk[(size_t)(n0 + rb + lr) * 512 + k0 + lcs], &Bs[rb * 64]);
    }
    __syncthreads();  // drains vmcnt(0) -> staged data visible
#pragma unroll
    for (int kk = 0; kk < 64; kk += 32) {
      const int cshift = (((kk >> 3) + l4) ^ s7) * 8;  // swizzled read col (u16)
      bf16x8 af[4], bfr[4];
#pragma unroll
      for (int mf = 0; mf < 4; ++mf)
        af[mf] = *(const bf16x8*)&As[(wm + mf * 16 + l15) * 64 + cshift];
#pragma unroll
      for (int nf = 0; nf < 4; ++nf)
        bfr[nf] = *(const bf16x8*)&Bs[(wn + nf * 16 + l15) * 64 + cshift];
#pragma unroll
      for (int mf = 0; mf < 4; ++mf)
#pragma unroll
        for (int nf = 0; nf < 4; ++nf)
          acc[mf][nf] = __builtin_amdgcn_mfma_f32_16x16x32_bf16(af[mf], bfr[nf], acc[mf][nf], 0, 0, 0);
    }
  }
  float bias[4];
#pragma unroll
  for (int nf = 0; nf < 4; ++nf) bias[nf] = bqk[n0 + wn + nf * 16 + l15];
  __syncthreads();
  u16* Cs = smem;  // [128][136]
#pragma unroll
  for (int mf = 0; mf < 4; ++mf)
#pragma unroll
    for (int nf = 0; nf < 4; ++nf)
#pragma unroll
      for (int r = 0; r < 4; ++r)
        Cs[(wm + mf * 16 + l4 * 4 + r) * 136 + wn + nf * 16 + l15] =
            f2bf(acc[mf][nf][r] + bias[nf]);
  __syncthreads();
#pragma unroll
  for (int rr = 0; rr < 8; ++rr) {
    int row = rr * 16 + (tid >> 4), c8 = (tid & 15) * 8;
    *(u16x8*)&qk[(size_t)(m0 + row) * 1024 + n0 + c8] = *(const u16x8*)&Cs[row * 136 + c8];
  }
}

// ---------------- K2: per-(i,b) scores -> softmax -> head-mean -> w (bf16) ----------------
// 8 waves (512 thr): each wave owns 16 q-rows -> 2x waves/CU vs 4-wave version
// (latency-bound kernel: 16 barriers + 8 staging rounds per block).
__global__ __launch_bounds__(512) void k_scores(
    const u16* __restrict__ qk, const unsigned char* __restrict__ mask,
    u16* __restrict__ wbuf) {
  const int i = blockIdx.x, b = blockIdx.y;
  __shared__ u16 smem[2 * 128 * 72];
  u16* qs = smem;
  u16* ks = smem + 128 * 72;
  const int tid = threadIdx.x, lane = tid & 63, wid = tid >> 6;  // wid 0..7
  const int l15 = lane & 15, l4 = lane >> 4;
  float wacc[8][4];
#pragma unroll
  for (int nf = 0; nf < 8; ++nf)
#pragma unroll
    for (int r = 0; r < 4; ++r) wacc[nf][r] = 0.f;
  bool mk[8];
#pragma unroll
  for (int nf = 0; nf < 8; ++nf) mk[nf] = mask[i * 512 + b * 128 + nf * 16 + l15] != 0;
  const int arow = tid >> 3, acol = (tid & 7) * 8;  // arow 0..63
  const f32x4 fz = {0.f, 0.f, 0.f, 0.f};
  for (int h = 0; h < 8; ++h) {
    __syncthreads();
#pragma unroll
    for (int rr = 0; rr < 2; ++rr) {
      int row = rr * 64 + arow;
      int base = ((i * 128 + row) * 4 + b) * 1024 + h * 64 + acol;
      *(u16x8*)&qs[row * 72 + acol] = *(const u16x8*)&qk[base];
      *(u16x8*)&ks[row * 72 + acol] = *(const u16x8*)&qk[base + 512];
    }
    __syncthreads();
    f32x4 sc[8];
#pragma unroll
    for (int nf = 0; nf < 8; ++nf) sc[nf] = fz;
#pragma unroll
    for (int kk = 0; kk < 64; kk += 32) {
      bf16x8 a = *(const bf16x8*)&qs[(wid * 16 + l15) * 72 + kk + l4 * 8];
#pragma unroll
      for (int nf = 0; nf < 8; ++nf) {
        bf16x8 bb = *(const bf16x8*)&ks[(nf * 16 + l15) * 72 + kk + l4 * 8];
        sc[nf] = __builtin_amdgcn_mfma_f32_16x16x32_bf16(a, bb, sc[nf], 0, 0, 0);
      }
    }
#pragma unroll
    for (int r = 0; r < 4; ++r) {
      float mx = -3e38f;
#pragma unroll
      for (int nf = 0; nf < 8; ++nf) mx = fmaxf(mx, mk[nf] ? -3e38f : sc[nf][r]);
#pragma unroll
      for (int d = 1; d < 16; d <<= 1) mx = fmaxf(mx, __shfl_xor(mx, d, 64));
      float p[8], sum = 0.f;
#pragma unroll
      for (int nf = 0; nf < 8; ++nf) {
        p[nf] = mk[nf] ? 0.f : __expf(sc[nf][r] - mx);
        sum += p[nf];
      }
#pragma unroll
      for (int d = 1; d < 16; d <<= 1) sum += __shfl_xor(sum, d, 64);
      float inv = 0.125f / sum;
#pragma unroll
      for (int nf = 0; nf < 8; ++nf) wacc[nf][r] += p[nf] * inv;
    }
  }
#pragma unroll
  for (int nf = 0; nf < 8; ++nf)
#pragma unroll
    for (int r = 0; r < 4; ++r) {
      int t = wid * 16 + l4 * 4 + r;
      wbuf[((i * 4 + b) * 128 + t) * 128 + nf * 16 + l15] = f2bf(wacc[nf][r]);
    }
}

// ---------------- K3: x-mix, transpose fused ----------------
// per (i,b,hc): ST[h'][s] built in-LDS from stB (4-chunk T-scratch, relmix pattern),
// then acc[h'][t] = sum_s ST[h'][s] * WS[t][s]. stT buffer + its 67MB write eliminated.
__global__ __launch_bounds__(256) void k_xmix(
    const u16* __restrict__ stB, const u16* __restrict__ wbuf,
    u16* __restrict__ xbuf) {
  const int i = blockIdx.x, b = blockIdx.y, hc = blockIdx.z;
  __shared__ u16 smem[2 * 128 * 136];
  u16* ST = smem;              // [128][136] ST[h'][s]
  u16* WS = smem + 128 * 136;  // [128][136] WS[t][s]; T scratch overlays this
  u16* T = WS;                 // [32][136]
  const int tid = threadIdx.x, lane = tid & 63, wid = tid >> 6;
  const int l15 = lane & 15, l4 = lane >> 4;
  const int wh = (wid >> 1) * 64, wt = (wid & 1) * 64;
  const int sr = tid >> 3, hseg = (tid & 7) * 16;  // chunk-load (32 s-rows x 128 h)
  const int th = tid >> 1, sseg = (tid & 1) * 16;  // scatter (128 h x 32 s)
#pragma unroll
  for (int ch = 0; ch < 4; ++ch) {
    const int sbase = ch * 32;
    size_t gaddr = ((size_t)(i * 128 + sbase + sr) * 4 + b) * 512 + hc * 128 + hseg;
    u16x8 r0 = *(const u16x8*)&stB[gaddr];
    u16x8 r1 = *(const u16x8*)&stB[gaddr + 8];
    __syncthreads();  // previous chunk's T readers done
    *(u16x8*)&T[sr * 136 + hseg] = r0;
    *(u16x8*)&T[sr * 136 + hseg + 8] = r1;
    __syncthreads();
    u16x8 c0, c1;
#pragma unroll
    for (int j = 0; j < 8; ++j) c0[j] = T[(sseg + j) * 136 + th];
#pragma unroll
    for (int j = 0; j < 8; ++j) c1[j] = T[(sseg + 8 + j) * 136 + th];
    *(u16x8*)&ST[th * 136 + sbase + sseg] = c0;
    *(u16x8*)&ST[th * 136 + sbase + sseg + 8] = c1;
  }
  __syncthreads();  // last chunk's T readers done before WS fill overwrites T
  const int r16 = tid >> 4, c8 = (tid & 15) * 8;
#pragma unroll
  for (int rr = 0; rr < 8; ++rr) {
    int row = rr * 16 + r16;
    *(u16x8*)&WS[row * 136 + c8] =
        *(const u16x8*)&wbuf[((i * 4 + b) * 128 + row) * 128 + c8];
  }
  __syncthreads();
  const f32x4 fz = {0.f, 0.f, 0.f, 0.f};
  f32x4 acc[4][4];
#pragma unroll
  for (int a = 0; a < 4; ++a)
#pragma unroll
    for (int c = 0; c < 4; ++c) acc[a][c] = fz;
#pragma unroll
  for (int kk = 0; kk < 128; kk += 32) {
    bf16x8 af[4], bfr[4];
#pragma unroll
    for (int mf = 0; mf < 4; ++mf)
      af[mf] = *(const bf16x8*)&ST[(wh + mf * 16 + l15) * 136 + kk + l4 * 8];
#pragma unroll
    for (int nf = 0; nf < 4; ++nf)
      bfr[nf] = *(const bf16x8*)&WS[(wt + nf * 16 + l15) * 136 + kk + l4 * 8];
#pragma unroll
    for (int mf = 0; mf < 4; ++mf)
#pragma unroll
      for (int nf = 0; nf < 4; ++nf)
        acc[mf][nf] = __builtin_amdgcn_mfma_f32_16x16x32_bf16(af[mf], bfr[nf], acc[mf][nf], 0, 0, 0);
  }
  __syncthreads();
  u16* Cs = smem;  // [t][h] 128x136
#pragma unroll
  for (int mf = 0; mf < 4; ++mf)
#pragma unroll
    for (int nf = 0; nf < 4; ++nf) {
      int h0 = wh + mf * 16 + l4 * 4;
      int t = wt + nf * 16 + l15;
      u16x4 pk = { f2bf(acc[mf][nf][0]), f2bf(acc[mf][nf][1]),
                   f2bf(acc[mf][nf][2]), f2bf(acc[mf][nf][3]) };
      *(u16x4*)&Cs[t * 136 + h0] = pk;
    }
  __syncthreads();
#pragma unroll
  for (int rr = 0; rr < 8; ++rr) {
    int t = rr * 16 + r16;
    *(u16x8*)&xbuf[((i * 128 + t) * 4 + b) * 512 + hc * 128 + c8] =
        *(const u16x8*)&Cs[t * 136 + c8];
  }
}

// ---------------- K4: rel-mix, transpose fused ----------------
__global__ __launch_bounds__(256) void k_relmix(
    const float* __restrict__ relation, const u16* __restrict__ wbuf,
    u16* __restrict__ relbuf) {
  const int t = blockIdx.x, b = blockIdx.y, hc = blockIdx.z;
  __shared__ u16 smem[2 * 128 * 136];
  u16* RT = smem;              // [128][136] RT[h'][s]
  u16* WS = smem + 128 * 136;  // [128][136] WS[i][s]; T scratch overlays this
  u16* T = WS;                 // [32][136]
  const int tid = threadIdx.x, lane = tid & 63, wid = tid >> 6;
  const int l15 = lane & 15, l4 = lane >> 4;
  const int wh = (wid >> 1) * 64, wi = (wid & 1) * 64;
  const int sr = tid >> 3, hseg = (tid & 7) * 16;
  const int th = tid >> 1, sseg = (tid & 1) * 16;
#pragma unroll
  for (int ch = 0; ch < 4; ++ch) {
    const int sbase = ch * 32;
    size_t gaddr = (((size_t)(sbase + sr) * 128 + t) * 4 + b) * 512 + hc * 128 + hseg;
    f32x4 v0 = *(const f32x4*)&relation[gaddr];
    f32x4 v1 = *(const f32x4*)&relation[gaddr + 4];
    f32x4 v2 = *(const f32x4*)&relation[gaddr + 8];
    f32x4 v3 = *(const f32x4*)&relation[gaddr + 12];
    __syncthreads();
    *(u16x8*)&T[sr * 136 + hseg] = pack8(v0, v1);
    *(u16x8*)&T[sr * 136 + hseg + 8] = pack8(v2, v3);
    __syncthreads();
    u16x8 c0, c1;
#pragma unroll
    for (int j = 0; j < 8; ++j) c0[j] = T[(sseg + j) * 136 + th];
#pragma unroll
    for (int j = 0; j < 8; ++j) c1[j] = T[(sseg + 8 + j) * 136 + th];
    *(u16x8*)&RT[th * 136 + sbase + sseg] = c0;
    *(u16x8*)&RT[th * 136 + sbase + sseg + 8] = c1;
  }
  __syncthreads();
  const int r16 = tid >> 4, c8 = (tid & 15) * 8;
#pragma unroll
  for (int rr = 0; rr < 8; ++rr) {
    int row = rr * 16 + r16;
    *(u16x8*)&WS[row * 136 + c8] =
        *(const u16x8*)&wbuf[((row * 4 + b) * 128 + t) * 128 + c8];
  }
  __syncthreads();
  const f32x4 fz = {0.f, 0.f, 0.f, 0.f};
  f32x4 acc[4][4];
#pragma unroll
  for (int a = 0; a < 4; ++a)
#pragma unroll
    for (int c = 0; c < 4; ++c) acc[a][c] = fz;
#pragma unroll
  for (int kk = 0; kk < 128; kk += 32) {
    bf16x8 af[4], bfr[4];
#pragma unroll
    for (int mf = 0; mf < 4; ++mf)
      af[mf] = *(const bf16x8*)&RT[(wh + mf * 16 + l15) * 136 + kk + l4 * 8];
#pragma unroll
    for (int nf = 0; nf < 4; ++nf)
      bfr[nf] = *(const bf16x8*)&WS[(wi + nf * 16 + l15) * 136 + kk + l4 * 8];
#pragma unroll
    for (int mf = 0; mf < 4; ++mf)
#pragma unroll
      for (int nf = 0; nf < 4; ++nf)
        acc[mf][nf] = __builtin_amdgcn_mfma_f32_16x16x32_bf16(af[mf], bfr[nf], acc[mf][nf], 0, 0, 0);
  }
  __syncthreads();
  u16* Cs = smem;  // [i][h] 128x136
#pragma unroll
  for (int mf = 0; mf < 4; ++mf)
#pragma unroll
    for (int nf = 0; nf < 4; ++nf) {
      int h0 = wh + mf * 16 + l4 * 4;
      int ii = wi + nf * 16 + l15;
      u16x4 pk = { f2bf(acc[mf][nf][0]), f2bf(acc[mf][nf][1]),
                   f2bf(acc[mf][nf][2]), f2bf(acc[mf][nf][3]) };
      *(u16x4*)&Cs[ii * 136 + h0] = pk;
    }
  __syncthreads();
#pragma unroll
  for (int rr = 0; rr < 8; ++rr) {
    int ii = rr * 16 + r16;
    *(u16x8*)&relbuf[((ii * 128 + t) * 4 + b) * 512 + hc * 128 + c8] =
        *(const u16x8*)&Cs[ii * 136 + c8];
  }
}

// ---------------- K5a: out-proj GEMM (M=65536,N=512,K=1024) + bias + relu -> yb bf16 ----------------
__global__ __launch_bounds__(256) void k_proj(
    const u16* __restrict__ xbuf, const u16* __restrict__ relbuf,
    const u16* __restrict__ wp, const float* __restrict__ bp,
    u16* __restrict__ yb) {
  const int flat = blockIdx.x;
  const int xcd = flat & 7, local = flat >> 3;          // local 0..255
  const int m0 = (xcd * 64 + (local >> 2)) * 128;
  const int n0 = (local & 3) * 128;
  __shared__ u16 smem[17408];
  u16* As = smem;
  u16* Bs = smem + 8192;
  const int tid = threadIdx.x, lane = tid & 63, wid = tid >> 6;
  const int l15 = lane & 15, l4 = lane >> 4;
  const int wm = (wid >> 1) * 64, wn = (wid & 1) * 64;
  const int lr = lane >> 3;
  const int lcs = ((lane & 7) ^ lr) * 8;
  const int s7 = l15 & 7;
  const f32x4 fz = {0.f, 0.f, 0.f, 0.f};
  f32x4 acc[4][4];
#pragma unroll
  for (int a = 0; a < 4; ++a)
#pragma unroll
    for (int c = 0; c < 4; ++c) acc[a][c] = fz;
  for (int k0 = 0; k0 < 1024; k0 += 64) {
    if (k0) __syncthreads();
    const u16* abase = (k0 < 512) ? xbuf + k0 : relbuf + (k0 - 512);
#pragma unroll
    for (int j = 0; j < 4; ++j) {
      int rb = wid * 32 + j * 8;
      gload16(&abase[(size_t)(m0 + rb + lr) * 512 + lcs], &As[rb * 64]);
      gload16(&wp[(size_t)(n0 + rb + lr) * 1024 + k0 + lcs], &Bs[rb * 64]);
    }
    __syncthreads();
#pragma unroll
    for (int kk = 0; kk < 64; kk += 32) {
      const int cshift = (((kk >> 3) + l4) ^ s7) * 8;
      bf16x8 af[4], bfr[4];
#pragma unroll
      for (int mf = 0; mf < 4; ++mf)
        af[mf] = *(const bf16x8*)&As[(wm + mf * 16 + l15) * 64 + cshift];
#pragma unroll
      for (int nf = 0; nf < 4; ++nf)
        bfr[nf] = *(const bf16x8*)&Bs[(wn + nf * 16 + l15) * 64 + cshift];
#pragma unroll
      for (int mf = 0; mf < 4; ++mf)
#pragma unroll
        for (int nf = 0; nf < 4; ++nf)
          acc[mf][nf] = __builtin_amdgcn_mfma_f32_16x16x32_bf16(af[mf], bfr[nf], acc[mf][nf], 0, 0, 0);
    }
  }
  float bias[4];
#pragma unroll
  for (int nf = 0; nf < 4; ++nf) bias[nf] = bp[n0 + wn + nf * 16 + l15];
  __syncthreads();
  u16* Cs = smem;  // [128][136]
#pragma unroll
  for (int mf = 0; mf < 4; ++mf)
#pragma unroll
    for (int nf = 0; nf < 4; ++nf)
#pragma unroll
      for (int r = 0; r < 4; ++r)
        Cs[(wm + mf * 16 + l4 * 4 + r) * 136 + wn + nf * 16 + l15] =
            f2bf(fmaxf(acc[mf][nf][r] + bias[nf], 0.f));
  __syncthreads();
#pragma unroll
  for (int rr = 0; rr < 8; ++rr) {
    int row = rr * 16 + (tid >> 4), c8 = (tid & 15) * 8;
    *(u16x8*)&yb[(size_t)(m0 + row) * 512 + n0 + c8] = *(const u16x8*)&Cs[row * 136 + c8];
  }
}

// ---------------- K5b: residual + LayerNorm (memory-bound row pass) ----------------
// residual from stB (bf16, 67MB) instead of state (fp32, 134MB).
__global__ __launch_bounds__(256) void k_ln(
    const u16* __restrict__ yb, const u16* __restrict__ stB,
    const float* __restrict__ gamma, const float* __restrict__ beta,
    float* __restrict__ out) {
  const int tid = threadIdx.x, lane = tid & 63, wid = tid >> 6;
  f32x4 g0 = *(const f32x4*)&gamma[lane * 8];
  f32x4 g1 = *(const f32x4*)&gamma[lane * 8 + 4];
  f32x4 be0 = *(const f32x4*)&beta[lane * 8];
  f32x4 be1 = *(const f32x4*)&beta[lane * 8 + 4];
  for (int row = blockIdx.x * 4 + wid; row < 65536; row += gridDim.x * 4) {
    size_t gbase = (size_t)row * 512 + lane * 8;
    u16x8 yv = *(const u16x8*)&yb[gbase];
    u16x8 sv = *(const u16x8*)&stB[gbase];
    float y[8];
#pragma unroll
    for (int j = 0; j < 8; ++j) y[j] = bf2f(yv[j]) + bf2f(sv[j]);
    float sum = 0.f, sq = 0.f;
#pragma unroll
    for (int j = 0; j < 8; ++j) { sum += y[j]; sq += y[j] * y[j]; }
#pragma unroll
    for (int d = 1; d < 64; d <<= 1) { sum += __shfl_xor(sum, d, 64); sq += __shfl_xor(sq, d, 64); }
    float mu = sum * (1.f / 512.f);
    float var = sq * (1.f / 512.f) - mu * mu;
    float rs = rsqrtf(var + 1e-5f);
    f32x4 o0, o1;
#pragma unroll
    for (int j = 0; j < 4; ++j) o0[j] = g0[j] * (y[j] - mu) * rs + be0[j];
#pragma unroll
    for (int j = 0; j < 4; ++j) o1[j] = g1[j] * (y[4 + j] - mu) * rs + be1[j];
    *(f32x4*)&out[gbase] = o0;
    *(f32x4*)&out[gbase + 4] = o1;
  }
}

extern "C" void kernel_launch(void* const* d_in, const int* in_sizes, int n_in,
                              void* d_out, int out_size, void* d_ws, size_t ws_size,
                              hipStream_t stream) {
  const float* state = (const float*)d_in[0];
  const float* relation = (const float*)d_in[1];
  const unsigned char* mask = (const unsigned char*)d_in[2];
  const float* Wq = (const float*)d_in[4];
  const float* bq = (const float*)d_in[5];
  const float* Wk = (const float*)d_in[6];
  const float* bk = (const float*)d_in[7];
  const float* Wp = (const float*)d_in[8];
  const float* bp = (const float*)d_in[9];
  const float* gamma = (const float*)d_in[10];
  const float* beta = (const float*)d_in[11];
  float* out = (float*)d_out;
  char* ws = (char*)d_ws;

  // workspace layout (bytes); aliases (lifetimes disjoint):
  //   xbuf/relbuf alias qk (dead after k_scores)
  //   yb in old stT region (stT eliminated)
  //   stB read by k_qkproj, k_xmix, k_ln — nothing overwrites its region
  u16* qk     = (u16*)(ws);                    // 134,217,728
  u16* xbuf   = (u16*)(ws);                    //  67,108,864 (alias qk lower half)
  u16* relbuf = (u16*)(ws + 67108864);         //  67,108,864 (alias qk upper half)
  u16* yb     = (u16*)(ws + 134217728);        //  67,108,864
  u16* stB    = (u16*)(ws + 201326592);        //  67,108,864
  u16* wbuf   = (u16*)(ws + 268435456);        //  16,777,216
  u16* wqk    = (u16*)(ws + 285212672);        //   1,048,576
  u16* wp     = (u16*)(ws + 286261248);        //   1,048,576
  float* bqk  = (float*)(ws + 287309824);      //       4,096

  k_prep<<<2048, 256, 0, stream>>>(Wq, Wk, bq, bk, Wp, wqk, wp, bqk);
  k_cast<<<16384, 256, 0, stream>>>(state, stB);
  k_qkproj<<<4096, 256, 0, stream>>>(stB, wqk, bqk, qk);
  k_scores<<<dim3(128, 4), 512, 0, stream>>>(qk, mask, wbuf);
  k_xmix<<<dim3(128, 4, 4), 256, 0, stream>>>(stB, wbuf, xbuf);
  k_relmix<<<dim3(128, 4, 4), 256, 0, stream>>>(relation, wbuf, relbuf);
  k_proj<<<2048, 256, 0, stream>>>(xbuf, relbuf, wp, bp, yb);
  k_ln<<<2048, 256, 0, stream>>>(yb, stB, gamma, beta, out);
}